// Round 1
// baseline (4869.049 us; speedup 1.0000x reference)
//
#include <hip/hip_runtime.h>
#include <math.h>

#define NHEAD 4
#define CCH 128
#define HCD 512
#define SLOPE 0.2f
#define EPS_BN 1e-5f

// ---- float <-> order-preserving uint (for atomicMax on float scores) ----
__device__ __forceinline__ unsigned int ford(float f) {
    unsigned int u = __float_as_uint(f);
    return (u & 0x80000000u) ? ~u : (u | 0x80000000u);
}
__device__ __forceinline__ float funord(unsigned int u) {
    return (u & 0x80000000u) ? __uint_as_float(u & 0x7fffffffu) : __uint_as_float(~u);
}

// ---- layer 1 node transforms: x[N,9] @ W[9,512] + b, both l and r ----
__global__ void lin1_kernel(const float* __restrict__ x,
                            const float* __restrict__ Wl, const float* __restrict__ bl,
                            const float* __restrict__ Wr, const float* __restrict__ br,
                            float* __restrict__ xl, float* __restrict__ xr, int n) {
    int gid = blockIdx.x * blockDim.x + threadIdx.x;
    if (gid >= n * HCD) return;
    int node = gid >> 9;
    int c = gid & (HCD - 1);
    const float* xrow = x + node * 9;
    float a = bl[c], bz = br[c];
#pragma unroll
    for (int k = 0; k < 9; ++k) {
        float xv = xrow[k];
        a  = fmaf(xv, Wl[k * HCD + c], a);
        bz = fmaf(xv, Wr[k * HCD + c], bz);
    }
    xl[gid] = a;
    xr[gid] = bz;
}

// ---- fp32 tiled GEMM: C[M,512] = A[M,512] @ B[512,512] + bias ----
__global__ __launch_bounds__(256) void gemm512_kernel(
        const float* __restrict__ A, const float* __restrict__ B,
        const float* __restrict__ bias, float* __restrict__ Cmat, int M) {
    __shared__ float As[16][64];   // As[k][m]
    __shared__ float Bs[16][64];   // Bs[k][n]
    const int tid  = threadIdx.x;
    const int row0 = blockIdx.x * 64;
    const int col0 = blockIdx.y * 64;
    const int tm = (tid >> 4) * 4;       // 0..60
    const int tn = (tid & 15) * 4;       // 0..60
    const int ar = tid >> 2;             // 0..63
    const int ak = (tid & 3) * 4;        // 0,4,8,12
    const int bk = tid >> 4;             // 0..15
    const int bc = (tid & 15) * 4;       // 0..60
    const bool aok = (row0 + ar) < M;
    const float* aptr = A + (size_t)(row0 + ar) * 512;
    float acc[4][4] = {{0.f,0.f,0.f,0.f},{0.f,0.f,0.f,0.f},{0.f,0.f,0.f,0.f},{0.f,0.f,0.f,0.f}};
    for (int k0 = 0; k0 < 512; k0 += 16) {
        float4 av = aok ? *(const float4*)(aptr + k0 + ak) : make_float4(0.f,0.f,0.f,0.f);
        float4 bv = *(const float4*)(B + (size_t)(k0 + bk) * 512 + col0 + bc);
        __syncthreads();
        As[ak + 0][ar] = av.x;
        As[ak + 1][ar] = av.y;
        As[ak + 2][ar] = av.z;
        As[ak + 3][ar] = av.w;
        *(float4*)&Bs[bk][bc] = bv;
        __syncthreads();
#pragma unroll
        for (int kk = 0; kk < 16; ++kk) {
            float4 a4 = *(const float4*)&As[kk][tm];
            float4 b4 = *(const float4*)&Bs[kk][tn];
            acc[0][0] = fmaf(a4.x, b4.x, acc[0][0]);
            acc[0][1] = fmaf(a4.x, b4.y, acc[0][1]);
            acc[0][2] = fmaf(a4.x, b4.z, acc[0][2]);
            acc[0][3] = fmaf(a4.x, b4.w, acc[0][3]);
            acc[1][0] = fmaf(a4.y, b4.x, acc[1][0]);
            acc[1][1] = fmaf(a4.y, b4.y, acc[1][1]);
            acc[1][2] = fmaf(a4.y, b4.z, acc[1][2]);
            acc[1][3] = fmaf(a4.y, b4.w, acc[1][3]);
            acc[2][0] = fmaf(a4.z, b4.x, acc[2][0]);
            acc[2][1] = fmaf(a4.z, b4.y, acc[2][1]);
            acc[2][2] = fmaf(a4.z, b4.z, acc[2][2]);
            acc[2][3] = fmaf(a4.z, b4.w, acc[2][3]);
            acc[3][0] = fmaf(a4.w, b4.x, acc[3][0]);
            acc[3][1] = fmaf(a4.w, b4.y, acc[3][1]);
            acc[3][2] = fmaf(a4.w, b4.z, acc[3][2]);
            acc[3][3] = fmaf(a4.w, b4.w, acc[3][3]);
        }
    }
    float4 bb = *(const float4*)(bias + col0 + tn);
#pragma unroll
    for (int i = 0; i < 4; ++i) {
        int r = row0 + tm + i;
        if (r < M) {
            float4 o;
            o.x = acc[i][0] + bb.x;
            o.y = acc[i][1] + bb.y;
            o.z = acc[i][2] + bb.z;
            o.w = acc[i][3] + bb.w;
            *(float4*)(Cmat + (size_t)r * 512 + col0 + tn) = o;
        }
    }
}

// ---- per-(edge,head) attention logit + segment max ----
__global__ void edge_score_kernel(const float* __restrict__ xl, const float* __restrict__ xr,
                                  const int* __restrict__ esrc, const int* __restrict__ edst,
                                  const float* __restrict__ att,
                                  float* __restrict__ scores, unsigned int* __restrict__ emax,
                                  int E, int Etot) {
    int gid = blockIdx.x * blockDim.x + threadIdx.x;
    if (gid >= Etot * NHEAD) return;
    int e = gid >> 2;
    int hh = gid & 3;
    int src = (e < E) ? esrc[e] : (e - E);
    int dst = (e < E) ? edst[e] : (e - E);
    const float4* lrow = (const float4*)(xl + (size_t)src * HCD + hh * CCH);
    const float4* rrow = (const float4*)(xr + (size_t)dst * HCD + hh * CCH);
    const float4* arow = (const float4*)(att + hh * CCH);
    float acc = 0.f;
#pragma unroll 4
    for (int c4 = 0; c4 < CCH / 4; ++c4) {
        float4 l = lrow[c4];
        float4 r = rrow[c4];
        float4 a = arow[c4];
        float m;
        m = l.x + r.x; m = (m > 0.f) ? m : SLOPE * m; acc = fmaf(m, a.x, acc);
        m = l.y + r.y; m = (m > 0.f) ? m : SLOPE * m; acc = fmaf(m, a.y, acc);
        m = l.z + r.z; m = (m > 0.f) ? m : SLOPE * m; acc = fmaf(m, a.z, acc);
        m = l.w + r.w; m = (m > 0.f) ? m : SLOPE * m; acc = fmaf(m, a.w, acc);
    }
    scores[gid] = acc;
    atomicMax(&emax[dst * NHEAD + hh], ford(acc));
}

// ---- p = exp(e - max); segment sum of p ----
__global__ void edge_exp_kernel(const int* __restrict__ edst,
                                const unsigned int* __restrict__ emax,
                                float* __restrict__ scores, float* __restrict__ denom,
                                int E, int Etot) {
    int gid = blockIdx.x * blockDim.x + threadIdx.x;
    if (gid >= Etot * NHEAD) return;
    int e = gid >> 2;
    int hh = gid & 3;
    int dst = (e < E) ? edst[e] : (e - E);
    float m = funord(emax[dst * NHEAD + hh]);
    float p = expf(scores[gid] - m);
    scores[gid] = p;
    atomicAdd(&denom[dst * NHEAD + hh], p);
}

// ---- out[dst] += alpha * xl[src], atomically ----
__global__ void aggregate_kernel(const float* __restrict__ xl,
                                 const int* __restrict__ esrc, const int* __restrict__ edst,
                                 const float* __restrict__ p, const float* __restrict__ denom,
                                 float* __restrict__ out, int E, int Etot) {
    int gid = blockIdx.x * blockDim.x + threadIdx.x;
    if (gid >= Etot * NHEAD * (CCH / 4)) return;
    int c4 = gid & 31;
    int hh = (gid >> 5) & 3;
    int e = gid >> 7;
    int src = (e < E) ? esrc[e] : (e - E);
    int dst = (e < E) ? edst[e] : (e - E);
    float alpha = p[e * NHEAD + hh] / (denom[dst * NHEAD + hh] + 1e-16f);
    float4 v = *(const float4*)(xl + (size_t)src * HCD + hh * CCH + c4 * 4);
    float* o = out + (size_t)dst * HCD + hh * CCH + c4 * 4;
    atomicAdd(o + 0, alpha * v.x);
    atomicAdd(o + 1, alpha * v.y);
    atomicAdd(o + 2, alpha * v.z);
    atomicAdd(o + 3, alpha * v.w);
}

// ---- BatchNorm statistics: per-channel sum and sum-of-squares ----
__global__ void bn_stats_kernel(const float* __restrict__ h, float* __restrict__ sum,
                                float* __restrict__ sumsq, int n) {
    int c = blockIdx.y * blockDim.x + threadIdx.x;   // 0..511
    int r0 = blockIdx.x * 128;
    int r1 = min(r0 + 128, n);
    float s = 0.f, s2 = 0.f;
    for (int r = r0; r < r1; ++r) {
        float v = h[(size_t)r * HCD + c];
        s += v;
        s2 = fmaf(v, v, s2);
    }
    atomicAdd(&sum[c], s);
    atomicAdd(&sumsq[c], s2);
}

__global__ void bn_finalize_kernel(const float* __restrict__ sum, const float* __restrict__ sumsq,
                                   const float* __restrict__ g, const float* __restrict__ b,
                                   float* __restrict__ scale, float* __restrict__ shift, int n) {
    int c = threadIdx.x;   // 512
    float inv_n = 1.0f / (float)n;
    float mu = sum[c] * inv_n;
    float var = fmaxf(sumsq[c] * inv_n - mu * mu, 0.0f);
    float sc = g[c] * rsqrtf(var + EPS_BN);
    scale[c] = sc;
    shift[c] = b[c] - mu * sc;
}

__global__ void bn_apply_relu_kernel(float* __restrict__ h, const float* __restrict__ scale,
                                     const float* __restrict__ shift, int total4) {
    int gid = blockIdx.x * blockDim.x + threadIdx.x;
    if (gid >= total4) return;
    int c4 = gid & 127;
    float4 v = ((float4*)h)[gid];
    float4 sc = ((const float4*)scale)[c4];
    float4 sh = ((const float4*)shift)[c4];
    v.x = fmaxf(fmaf(v.x, sc.x, sh.x), 0.f);
    v.y = fmaxf(fmaf(v.y, sc.y, sh.y), 0.f);
    v.z = fmaxf(fmaf(v.z, sc.z, sh.z), 0.f);
    v.w = fmaxf(fmaf(v.w, sc.w, sh.w), 0.f);
    ((float4*)h)[gid] = v;
}

// ---- per-graph mean pool (batch is sorted) ----
__device__ __forceinline__ int lower_bound_i(const int* __restrict__ a, int n, int key) {
    int lo = 0, hi = n;
    while (lo < hi) {
        int mid = (lo + hi) >> 1;
        if (a[mid] < key) lo = mid + 1; else hi = mid;
    }
    return lo;
}

__global__ void pool_kernel(const float* __restrict__ h, const int* __restrict__ batch,
                            float* __restrict__ pooled, int n) {
    int g = blockIdx.x;
    int c = threadIdx.x;   // 512
    int start = lower_bound_i(batch, n, g);
    int end   = lower_bound_i(batch, n, g + 1);
    float s = 0.f;
    for (int r = start; r < end; ++r) s += h[(size_t)r * HCD + c];
    float cnt = (float)max(end - start, 1);
    pooled[(size_t)g * HCD + c] = s / cnt;
}

// ---- MLP head: relu([pooled|gfeat] @ fc1 + b1) @ fc2 + b2 ----
__global__ void head_kernel(const float* __restrict__ pooled, const float* __restrict__ gfeat,
                            const float* __restrict__ fc1w, const float* __restrict__ fc1b,
                            const float* __restrict__ fc2w, const float* __restrict__ fc2b,
                            float* __restrict__ out, int gdim) {
    int g = blockIdx.x;
    int j = threadIdx.x;   // 128
    float acc = fc1b[j];
    const float* prow = pooled + (size_t)g * HCD;
    for (int i = 0; i < HCD; ++i) acc = fmaf(prow[i], fc1w[i * CCH + j], acc);
    const float* grow = gfeat + (size_t)g * gdim;
    for (int i = 0; i < gdim; ++i) acc = fmaf(grow[i], fc1w[(HCD + i) * CCH + j], acc);
    acc = fmaxf(acc, 0.f);
    __shared__ float z[CCH];
    z[j] = acc * fc2w[j];
    __syncthreads();
    for (int s = CCH / 2; s > 0; s >>= 1) {
        if (j < s) z[j] += z[j + s];
        __syncthreads();
    }
    if (j == 0) out[g] = z[0] + fc2b[0];
}

extern "C" void kernel_launch(void* const* d_in, const int* in_sizes, int n_in,
                              void* d_out, int out_size, void* d_ws, size_t ws_size,
                              hipStream_t stream) {
    const float* x     = (const float*)d_in[0];
    const float* gfeat = (const float*)d_in[1];
    const float* W1l   = (const float*)d_in[2];
    const float* b1l   = (const float*)d_in[3];
    const float* W1r   = (const float*)d_in[4];
    const float* b1r   = (const float*)d_in[5];
    const float* att1  = (const float*)d_in[6];
    // d_in[7] = bias1: per-channel constant added right before BatchNorm -> cancels exactly; skipped
    const float* W2l   = (const float*)d_in[8];
    const float* b2l   = (const float*)d_in[9];
    const float* W2r   = (const float*)d_in[10];
    const float* b2r   = (const float*)d_in[11];
    const float* att2  = (const float*)d_in[12];
    // d_in[13] = bias2: cancels through BN; skipped
    const float* bn1_g = (const float*)d_in[14];
    const float* bn1_b = (const float*)d_in[15];
    const float* bn2_g = (const float*)d_in[16];
    const float* bn2_b = (const float*)d_in[17];
    const float* fc1w  = (const float*)d_in[18];
    const float* fc1b  = (const float*)d_in[19];
    const float* fc2w  = (const float*)d_in[20];
    const float* fc2b  = (const float*)d_in[21];
    const int* eidx    = (const int*)d_in[22];
    const int* batch   = (const int*)d_in[23];

    const int n    = in_sizes[0] / 9;
    const int E    = in_sizes[22] / 2;
    const int Etot = E + n;
    const int b    = out_size;
    const int gdim = in_sizes[1] / b;
    const int* esrc = eidx;
    const int* edst = eidx + E;

    float* ws = (float*)d_ws;
    size_t nHC = (size_t)n * HCD;
    float* xl      = ws;
    float* xr      = xl + nHC;
    float* hbuf    = xr + nHC;
    float* scores  = hbuf + nHC;                               // Etot*NHEAD
    unsigned int* emax = (unsigned int*)(scores + (size_t)Etot * NHEAD);  // n*NHEAD
    float* denom   = (float*)emax + (size_t)n * NHEAD;         // n*NHEAD
    float* bnsum   = denom + (size_t)n * NHEAD;                // 512
    float* bnsumsq = bnsum + HCD;                              // 512
    float* bnscale = bnsumsq + HCD;                            // 512
    float* bnshift = bnscale + HCD;                            // 512
    float* pooled  = bnshift + HCD;                            // b*512

    const int BLK = 256;
    const int linBlocks  = (int)((nHC + BLK - 1) / BLK);
    const int edgeBlocks = (Etot * NHEAD + BLK - 1) / BLK;
    const int aggBlocks  = (int)(((size_t)Etot * NHEAD * (CCH / 4) + BLK - 1) / BLK);
    const int bnxBlocks  = (n + 127) / 128;
    const int bnaBlocks  = (int)((nHC / 4 + BLK - 1) / BLK);
    dim3 gemmGrid((n + 63) / 64, 512 / 64);

    // ---------------- layer 1 ----------------
    lin1_kernel<<<linBlocks, BLK, 0, stream>>>(x, W1l, b1l, W1r, b1r, xl, xr, n);
    hipMemsetAsync(emax, 0, (size_t)n * NHEAD * 4 * 2, stream);  // emax (ordered -inf == 0) + denom
    edge_score_kernel<<<edgeBlocks, BLK, 0, stream>>>(xl, xr, esrc, edst, att1, scores, emax, E, Etot);
    edge_exp_kernel<<<edgeBlocks, BLK, 0, stream>>>(edst, emax, scores, denom, E, Etot);
    hipMemsetAsync(hbuf, 0, nHC * sizeof(float), stream);
    aggregate_kernel<<<aggBlocks, BLK, 0, stream>>>(xl, esrc, edst, scores, denom, hbuf, E, Etot);
    hipMemsetAsync(bnsum, 0, HCD * 2 * sizeof(float), stream);
    bn_stats_kernel<<<dim3(bnxBlocks, 2), BLK, 0, stream>>>(hbuf, bnsum, bnsumsq, n);
    bn_finalize_kernel<<<1, HCD, 0, stream>>>(bnsum, bnsumsq, bn1_g, bn1_b, bnscale, bnshift, n);
    bn_apply_relu_kernel<<<bnaBlocks, BLK, 0, stream>>>(hbuf, bnscale, bnshift, (int)(nHC / 4));

    // ---------------- layer 2 ----------------
    gemm512_kernel<<<gemmGrid, BLK, 0, stream>>>(hbuf, W2l, b2l, xl, n);
    gemm512_kernel<<<gemmGrid, BLK, 0, stream>>>(hbuf, W2r, b2r, xr, n);
    hipMemsetAsync(emax, 0, (size_t)n * NHEAD * 4 * 2, stream);
    edge_score_kernel<<<edgeBlocks, BLK, 0, stream>>>(xl, xr, esrc, edst, att2, scores, emax, E, Etot);
    edge_exp_kernel<<<edgeBlocks, BLK, 0, stream>>>(edst, emax, scores, denom, E, Etot);
    hipMemsetAsync(hbuf, 0, nHC * sizeof(float), stream);
    aggregate_kernel<<<aggBlocks, BLK, 0, stream>>>(xl, esrc, edst, scores, denom, hbuf, E, Etot);
    hipMemsetAsync(bnsum, 0, HCD * 2 * sizeof(float), stream);
    bn_stats_kernel<<<dim3(bnxBlocks, 2), BLK, 0, stream>>>(hbuf, bnsum, bnsumsq, n);
    bn_finalize_kernel<<<1, HCD, 0, stream>>>(bnsum, bnsumsq, bn2_g, bn2_b, bnscale, bnshift, n);
    bn_apply_relu_kernel<<<bnaBlocks, BLK, 0, stream>>>(hbuf, bnscale, bnshift, (int)(nHC / 4));

    // ---------------- readout ----------------
    pool_kernel<<<b, HCD, 0, stream>>>(hbuf, batch, pooled, n);
    head_kernel<<<b, CCH, 0, stream>>>(pooled, gfeat, fc1w, fc1b, fc2w, fc2b, (float*)d_out, gdim);
}

// Round 5
// 1578.977 us; speedup vs baseline: 3.0837x; 3.0837x over previous
//
#include <hip/hip_runtime.h>
#include <math.h>

#define NHEAD 4
#define CCH 128
#define HCD 512
#define SLOPE 0.2f
#define EPS_BN 1e-5f

// ---- layer 1 node transforms: x[N,9] @ W[9,512] + b, both l and r ----
__global__ void lin1_kernel(const float* __restrict__ x,
                            const float* __restrict__ Wl, const float* __restrict__ bl,
                            const float* __restrict__ Wr, const float* __restrict__ br,
                            float* __restrict__ xl, float* __restrict__ xr, int n) {
    int gid = blockIdx.x * blockDim.x + threadIdx.x;
    if (gid >= n * HCD) return;
    int node = gid >> 9;
    int c = gid & (HCD - 1);
    const float* xrow = x + node * 9;
    float a = bl[c], bz = br[c];
#pragma unroll
    for (int k = 0; k < 9; ++k) {
        float xv = xrow[k];
        a  = fmaf(xv, Wl[k * HCD + c], a);
        bz = fmaf(xv, Wr[k * HCD + c], bz);
    }
    xl[gid] = a;
    xr[gid] = bz;
}

// ---- fp32 tiled GEMM: C[M,512] = A[M,512] @ B[512,512] + bias ----
__global__ __launch_bounds__(256) void gemm512_kernel(
        const float* __restrict__ A, const float* __restrict__ B,
        const float* __restrict__ bias, float* __restrict__ Cmat, int M) {
    __shared__ float As[16][64];   // As[k][m]
    __shared__ float Bs[16][64];   // Bs[k][n]
    const int tid  = threadIdx.x;
    const int row0 = blockIdx.x * 64;
    const int col0 = blockIdx.y * 64;
    const int tm = (tid >> 4) * 4;       // 0..60
    const int tn = (tid & 15) * 4;       // 0..60
    const int ar = tid >> 2;             // 0..63
    const int ak = (tid & 3) * 4;        // 0,4,8,12
    const int bk = tid >> 4;             // 0..15
    const int bc = (tid & 15) * 4;       // 0..60
    const bool aok = (row0 + ar) < M;
    const float* aptr = A + (size_t)(row0 + ar) * 512;
    float acc[4][4] = {{0.f,0.f,0.f,0.f},{0.f,0.f,0.f,0.f},{0.f,0.f,0.f,0.f},{0.f,0.f,0.f,0.f}};
    for (int k0 = 0; k0 < 512; k0 += 16) {
        float4 av = aok ? *(const float4*)(aptr + k0 + ak) : make_float4(0.f,0.f,0.f,0.f);
        float4 bv = *(const float4*)(B + (size_t)(k0 + bk) * 512 + col0 + bc);
        __syncthreads();
        As[ak + 0][ar] = av.x;
        As[ak + 1][ar] = av.y;
        As[ak + 2][ar] = av.z;
        As[ak + 3][ar] = av.w;
        *(float4*)&Bs[bk][bc] = bv;
        __syncthreads();
#pragma unroll
        for (int kk = 0; kk < 16; ++kk) {
            float4 a4 = *(const float4*)&As[kk][tm];
            float4 b4 = *(const float4*)&Bs[kk][tn];
            acc[0][0] = fmaf(a4.x, b4.x, acc[0][0]);
            acc[0][1] = fmaf(a4.x, b4.y, acc[0][1]);
            acc[0][2] = fmaf(a4.x, b4.z, acc[0][2]);
            acc[0][3] = fmaf(a4.x, b4.w, acc[0][3]);
            acc[1][0] = fmaf(a4.y, b4.x, acc[1][0]);
            acc[1][1] = fmaf(a4.y, b4.y, acc[1][1]);
            acc[1][2] = fmaf(a4.y, b4.z, acc[1][2]);
            acc[1][3] = fmaf(a4.y, b4.w, acc[1][3]);
            acc[2][0] = fmaf(a4.z, b4.x, acc[2][0]);
            acc[2][1] = fmaf(a4.z, b4.y, acc[2][1]);
            acc[2][2] = fmaf(a4.z, b4.z, acc[2][2]);
            acc[2][3] = fmaf(a4.z, b4.w, acc[2][3]);
            acc[3][0] = fmaf(a4.w, b4.x, acc[3][0]);
            acc[3][1] = fmaf(a4.w, b4.y, acc[3][1]);
            acc[3][2] = fmaf(a4.w, b4.z, acc[3][2]);
            acc[3][3] = fmaf(a4.w, b4.w, acc[3][3]);
        }
    }
    float4 bb = *(const float4*)(bias + col0 + tn);
#pragma unroll
    for (int i = 0; i < 4; ++i) {
        int r = row0 + tm + i;
        if (r < M) {
            float4 o;
            o.x = acc[i][0] + bb.x;
            o.y = acc[i][1] + bb.y;
            o.z = acc[i][2] + bb.z;
            o.w = acc[i][3] + bb.w;
            *(float4*)(Cmat + (size_t)r * 512 + col0 + tn) = o;
        }
    }
}

// ================= CSR build (once per launch; graph shared by both layers) =================

__global__ void hist_kernel(const int* __restrict__ edst, int* __restrict__ deg, int E, int Etot) {
    int e = blockIdx.x * blockDim.x + threadIdx.x;
    if (e >= Etot) return;
    int dst = (e < E) ? edst[e] : (e - E);
    atomicAdd(&deg[dst], 1);
}

// single-workgroup exclusive scan over n (+ total at rowstart[n])
__global__ __launch_bounds__(1024) void scan_kernel(const int* __restrict__ deg,
                                                    int* __restrict__ rowstart, int n) {
    __shared__ int buf[1024];
    __shared__ int carry;
    if (threadIdx.x == 0) carry = 0;
    __syncthreads();
    for (int base = 0; base < n; base += 1024) {
        int i = base + (int)threadIdx.x;
        int v = (i < n) ? deg[i] : 0;
        buf[threadIdx.x] = v;
        __syncthreads();
        for (int off = 1; off < 1024; off <<= 1) {
            int t = (threadIdx.x >= (unsigned)off) ? buf[threadIdx.x - off] : 0;
            __syncthreads();
            buf[threadIdx.x] += t;
            __syncthreads();
        }
        if (i < n) rowstart[i] = carry + buf[threadIdx.x] - v;
        int blocksum = buf[1023];
        __syncthreads();
        if (threadIdx.x == 0) carry += blocksum;
        __syncthreads();
    }
    if (threadIdx.x == 0) rowstart[n] = carry;
}

// assigns each edge its slot in the dst-sorted order; records src per slot and slot per edge
__global__ void scatter_kernel(const int* __restrict__ esrc, const int* __restrict__ edst,
                               const int* __restrict__ rowstart, int* __restrict__ cursor,
                               int* __restrict__ s_src, int* __restrict__ s_pos, int E, int Etot) {
    int e = blockIdx.x * blockDim.x + threadIdx.x;
    if (e >= Etot) return;
    int src = (e < E) ? esrc[e] : (e - E);
    int dst = (e < E) ? edst[e] : (e - E);
    int pos = rowstart[dst] + atomicAdd(&cursor[dst], 1);
    s_src[pos] = src;
    s_pos[e] = pos;
}

// ---- per-(edge,head) attention logit, written at the CSR slot (no atomics) ----
__global__ void edge_score_kernel(const float* __restrict__ xl, const float* __restrict__ xr,
                                  const int* __restrict__ esrc, const int* __restrict__ edst,
                                  const int* __restrict__ s_pos, const float* __restrict__ att,
                                  float* __restrict__ scores, int E, int Etot) {
    int gid = blockIdx.x * blockDim.x + threadIdx.x;
    if (gid >= Etot * NHEAD) return;
    int e = gid >> 2;
    int hh = gid & 3;
    int src = (e < E) ? esrc[e] : (e - E);
    int dst = (e < E) ? edst[e] : (e - E);
    const float4* lrow = (const float4*)(xl + (size_t)src * HCD + hh * CCH);
    const float4* rrow = (const float4*)(xr + (size_t)dst * HCD + hh * CCH);
    const float4* arow = (const float4*)(att + hh * CCH);
    float acc = 0.f;
#pragma unroll 4
    for (int c4 = 0; c4 < CCH / 4; ++c4) {
        float4 l = lrow[c4];
        float4 r = rrow[c4];
        float4 a = arow[c4];
        float m;
        m = l.x + r.x; m = (m > 0.f) ? m : SLOPE * m; acc = fmaf(m, a.x, acc);
        m = l.y + r.y; m = (m > 0.f) ? m : SLOPE * m; acc = fmaf(m, a.y, acc);
        m = l.z + r.z; m = (m > 0.f) ? m : SLOPE * m; acc = fmaf(m, a.z, acc);
        m = l.w + r.w; m = (m > 0.f) ? m : SLOPE * m; acc = fmaf(m, a.w, acc);
    }
    scores[s_pos[e] * NHEAD + hh] = acc;
}

// ---- fused softmax + aggregation, one workgroup per dst node ----
// wave h handles head h; each lane owns 2 consecutive channels.
// scores are CSR-ordered, so each node's logits are contiguous.
__global__ __launch_bounds__(256) void aggregate_csr_kernel(
        const float* __restrict__ xl, const float* __restrict__ scores,
        const int* __restrict__ rowstart, const int* __restrict__ s_src,
        float* __restrict__ out) {
    int node = blockIdx.x;
    int wave = threadIdx.x >> 6;         // head 0..3
    int lane = threadIdx.x & 63;
    int beg = rowstart[node];
    int end = rowstart[node + 1];
    int c0 = wave * CCH + lane * 2;
    float m = -1e30f;
    for (int j = beg; j < end; ++j)
        m = fmaxf(m, scores[j * NHEAD + wave]);
    float den = 0.f, a0 = 0.f, a1 = 0.f;
    for (int j = beg; j < end; ++j) {
        float p = expf(scores[j * NHEAD + wave] - m);
        den += p;
        float2 v = *(const float2*)(xl + (size_t)s_src[j] * HCD + c0);
        a0 = fmaf(p, v.x, a0);
        a1 = fmaf(p, v.y, a1);
    }
    float inv = 1.0f / (den + 1e-16f);
    float2 o;
    o.x = a0 * inv;
    o.y = a1 * inv;
    *(float2*)(out + (size_t)node * HCD + c0) = o;
}

// ---- BatchNorm statistics: per-channel sum and sum-of-squares ----
__global__ void bn_stats_kernel(const float* __restrict__ h, float* __restrict__ sum,
                                float* __restrict__ sumsq, int n) {
    int c = blockIdx.y * blockDim.x + threadIdx.x;   // 0..511
    int r0 = blockIdx.x * 128;
    int r1 = min(r0 + 128, n);
    float s = 0.f, s2 = 0.f;
    for (int r = r0; r < r1; ++r) {
        float v = h[(size_t)r * HCD + c];
        s += v;
        s2 = fmaf(v, v, s2);
    }
    atomicAdd(&sum[c], s);
    atomicAdd(&sumsq[c], s2);
}

__global__ void bn_finalize_kernel(const float* __restrict__ sum, const float* __restrict__ sumsq,
                                   const float* __restrict__ g, const float* __restrict__ b,
                                   float* __restrict__ scale, float* __restrict__ shift, int n) {
    int c = threadIdx.x;   // 512
    float inv_n = 1.0f / (float)n;
    float mu = sum[c] * inv_n;
    float var = fmaxf(sumsq[c] * inv_n - mu * mu, 0.0f);
    float sc = g[c] * rsqrtf(var + EPS_BN);
    scale[c] = sc;
    shift[c] = b[c] - mu * sc;
}

__global__ void bn_apply_relu_kernel(float* __restrict__ h, const float* __restrict__ scale,
                                     const float* __restrict__ shift, int total4) {
    int gid = blockIdx.x * blockDim.x + threadIdx.x;
    if (gid >= total4) return;
    int c4 = gid & 127;
    float4 v = ((float4*)h)[gid];
    float4 sc = ((const float4*)scale)[c4];
    float4 sh = ((const float4*)shift)[c4];
    v.x = fmaxf(fmaf(v.x, sc.x, sh.x), 0.f);
    v.y = fmaxf(fmaf(v.y, sc.y, sh.y), 0.f);
    v.z = fmaxf(fmaf(v.z, sc.z, sh.z), 0.f);
    v.w = fmaxf(fmaf(v.w, sc.w, sh.w), 0.f);
    ((float4*)h)[gid] = v;
}

// ---- per-graph mean pool (batch is sorted) ----
__device__ __forceinline__ int lower_bound_i(const int* __restrict__ a, int n, int key) {
    int lo = 0, hi = n;
    while (lo < hi) {
        int mid = (lo + hi) >> 1;
        if (a[mid] < key) lo = mid + 1; else hi = mid;
    }
    return lo;
}

__global__ void pool_kernel(const float* __restrict__ h, const int* __restrict__ batch,
                            float* __restrict__ pooled, int n) {
    int g = blockIdx.x;
    int c = threadIdx.x;   // 512
    int start = lower_bound_i(batch, n, g);
    int end   = lower_bound_i(batch, n, g + 1);
    float s = 0.f;
    for (int r = start; r < end; ++r) s += h[(size_t)r * HCD + c];
    float cnt = (float)max(end - start, 1);
    pooled[(size_t)g * HCD + c] = s / cnt;
}

// ---- MLP head: relu([pooled|gfeat] @ fc1 + b1) @ fc2 + b2 ----
__global__ void head_kernel(const float* __restrict__ pooled, const float* __restrict__ gfeat,
                            const float* __restrict__ fc1w, const float* __restrict__ fc1b,
                            const float* __restrict__ fc2w, const float* __restrict__ fc2b,
                            float* __restrict__ out, int gdim) {
    int g = blockIdx.x;
    int j = threadIdx.x;   // 128
    float acc = fc1b[j];
    const float* prow = pooled + (size_t)g * HCD;
    for (int i = 0; i < HCD; ++i) acc = fmaf(prow[i], fc1w[i * CCH + j], acc);
    const float* grow = gfeat + (size_t)g * gdim;
    for (int i = 0; i < gdim; ++i) acc = fmaf(grow[i], fc1w[(HCD + i) * CCH + j], acc);
    acc = fmaxf(acc, 0.f);
    __shared__ float z[CCH];
    z[j] = acc * fc2w[j];
    __syncthreads();
    for (int s = CCH / 2; s > 0; s >>= 1) {
        if (j < s) z[j] += z[j + s];
        __syncthreads();
    }
    if (j == 0) out[g] = z[0] + fc2b[0];
}

extern "C" void kernel_launch(void* const* d_in, const int* in_sizes, int n_in,
                              void* d_out, int out_size, void* d_ws, size_t ws_size,
                              hipStream_t stream) {
    const float* x     = (const float*)d_in[0];
    const float* gfeat = (const float*)d_in[1];
    const float* W1l   = (const float*)d_in[2];
    const float* b1l   = (const float*)d_in[3];
    const float* W1r   = (const float*)d_in[4];
    const float* b1r   = (const float*)d_in[5];
    const float* att1  = (const float*)d_in[6];
    // d_in[7] = bias1: per-channel constant added right before BatchNorm -> cancels exactly
    const float* W2l   = (const float*)d_in[8];
    const float* b2l   = (const float*)d_in[9];
    const float* W2r   = (const float*)d_in[10];
    const float* b2r   = (const float*)d_in[11];
    const float* att2  = (const float*)d_in[12];
    // d_in[13] = bias2: cancels through BN
    const float* bn1_g = (const float*)d_in[14];
    const float* bn1_b = (const float*)d_in[15];
    const float* bn2_g = (const float*)d_in[16];
    const float* bn2_b = (const float*)d_in[17];
    const float* fc1w  = (const float*)d_in[18];
    const float* fc1b  = (const float*)d_in[19];
    const float* fc2w  = (const float*)d_in[20];
    const float* fc2b  = (const float*)d_in[21];
    const int* eidx    = (const int*)d_in[22];
    const int* batch   = (const int*)d_in[23];

    const int n    = in_sizes[0] / 9;
    const int E    = in_sizes[22] / 2;
    const int Etot = E + n;
    const int b    = out_size;
    const int gdim = in_sizes[1] / b;
    const int* esrc = eidx;
    const int* edst = eidx + E;

    float* ws = (float*)d_ws;
    size_t nHC = (size_t)n * HCD;
    float* xl      = ws;
    float* xr      = xl + nHC;
    float* hbuf    = xr + nHC;
    float* scores  = hbuf + nHC;                            // Etot*NHEAD floats
    int* deg       = (int*)(scores + (size_t)Etot * NHEAD); // n
    int* rowstart  = deg + n;                               // n+1
    int* cursor    = rowstart + n + 1;                      // n
    int* s_src     = cursor + n;                            // Etot
    int* s_pos     = s_src + Etot;                          // Etot
    float* bnsum   = (float*)(s_pos + Etot);                // 512
    float* bnsumsq = bnsum + HCD;                           // 512
    float* bnscale = bnsumsq + HCD;                         // 512
    float* bnshift = bnscale + HCD;                         // 512
    float* pooled  = bnshift + HCD;                         // b*512

    const int BLK = 256;
    const int linBlocks  = (int)((nHC + BLK - 1) / BLK);
    const int edgeBlocks = (Etot * NHEAD + BLK - 1) / BLK;
    const int eBlocks    = (Etot + BLK - 1) / BLK;
    const int bnxBlocks  = (n + 127) / 128;
    const int bnaBlocks  = (int)((nHC / 4 + BLK - 1) / BLK);
    dim3 gemmGrid((n + 63) / 64, 512 / 64);

    // ---------------- CSR build (shared by both layers) ----------------
    hipMemsetAsync(deg, 0, (size_t)(2 * n + 1) * sizeof(int), stream);  // deg + rowstart head
    hipMemsetAsync(cursor, 0, (size_t)n * sizeof(int), stream);
    hist_kernel<<<eBlocks, BLK, 0, stream>>>(edst, deg, E, Etot);
    scan_kernel<<<1, 1024, 0, stream>>>(deg, rowstart, n);
    scatter_kernel<<<eBlocks, BLK, 0, stream>>>(esrc, edst, rowstart, cursor, s_src, s_pos, E, Etot);

    // ---------------- layer 1 ----------------
    lin1_kernel<<<linBlocks, BLK, 0, stream>>>(x, W1l, b1l, W1r, b1r, xl, xr, n);
    edge_score_kernel<<<edgeBlocks, BLK, 0, stream>>>(xl, xr, esrc, edst, s_pos, att1, scores, E, Etot);
    aggregate_csr_kernel<<<n, 256, 0, stream>>>(xl, scores, rowstart, s_src, hbuf);
    hipMemsetAsync(bnsum, 0, HCD * 2 * sizeof(float), stream);
    bn_stats_kernel<<<dim3(bnxBlocks, 2), BLK, 0, stream>>>(hbuf, bnsum, bnsumsq, n);
    bn_finalize_kernel<<<1, HCD, 0, stream>>>(bnsum, bnsumsq, bn1_g, bn1_b, bnscale, bnshift, n);
    bn_apply_relu_kernel<<<bnaBlocks, BLK, 0, stream>>>(hbuf, bnscale, bnshift, (int)(nHC / 4));

    // ---------------- layer 2 ----------------
    gemm512_kernel<<<gemmGrid, BLK, 0, stream>>>(hbuf, W2l, b2l, xl, n);
    gemm512_kernel<<<gemmGrid, BLK, 0, stream>>>(hbuf, W2r, b2r, xr, n);
    edge_score_kernel<<<edgeBlocks, BLK, 0, stream>>>(xl, xr, esrc, edst, s_pos, att2, scores, E, Etot);
    aggregate_csr_kernel<<<n, 256, 0, stream>>>(xl, scores, rowstart, s_src, hbuf);
    hipMemsetAsync(bnsum, 0, HCD * 2 * sizeof(float), stream);
    bn_stats_kernel<<<dim3(bnxBlocks, 2), BLK, 0, stream>>>(hbuf, bnsum, bnsumsq, n);
    bn_finalize_kernel<<<1, HCD, 0, stream>>>(bnsum, bnsumsq, bn2_g, bn2_b, bnscale, bnshift, n);
    bn_apply_relu_kernel<<<bnaBlocks, BLK, 0, stream>>>(hbuf, bnscale, bnshift, (int)(nHC / 4));

    // ---------------- readout ----------------
    pool_kernel<<<b, HCD, 0, stream>>>(hbuf, batch, pooled, n);
    head_kernel<<<b, CCH, 0, stream>>>(pooled, gfeat, fc1w, fc1b, fc2w, fc2b, (float*)d_out, gdim);
}

// Round 6
// 1264.309 us; speedup vs baseline: 3.8512x; 1.2489x over previous
//
#include <hip/hip_runtime.h>
#include <math.h>

#define NHEAD 4
#define CCH 128
#define HCD 512
#define SLOPE 0.2f
#define EPS_BN 1e-5f

// ---- layer 1 node transforms: x[N,9] @ W[9,512] + b, both l and r ----
__global__ void lin1_kernel(const float* __restrict__ x,
                            const float* __restrict__ Wl, const float* __restrict__ bl,
                            const float* __restrict__ Wr, const float* __restrict__ br,
                            float* __restrict__ xl, float* __restrict__ xr, int n) {
    int gid = blockIdx.x * blockDim.x + threadIdx.x;
    if (gid >= n * HCD) return;
    int node = gid >> 9;
    int c = gid & (HCD - 1);
    const float* xrow = x + node * 9;
    float a = bl[c], bz = br[c];
#pragma unroll
    for (int k = 0; k < 9; ++k) {
        float xv = xrow[k];
        a  = fmaf(xv, Wl[k * HCD + c], a);
        bz = fmaf(xv, Wr[k * HCD + c], bz);
    }
    xl[gid] = a;
    xr[gid] = bz;
}

// ---- fp32 tiled GEMM with fused input BN+ReLU:
//      C[M,512] = relu(A*aScale+aShift) @ B[512,512] + bias
// micro-tile uses strided float2 pairs (2tx / 2tx+32) -> conflict-free LDS reads
__global__ __launch_bounds__(256) void gemm512_bnrelu_kernel(
        const float* __restrict__ A, const float* __restrict__ B,
        const float* __restrict__ aScale, const float* __restrict__ aShift,
        const float* __restrict__ bias, float* __restrict__ Cmat, int M) {
    __shared__ float As[16][64];   // As[k][m]
    __shared__ float Bs[16][64];   // Bs[k][n]
    const int tid  = threadIdx.x;
    const int row0 = blockIdx.x * 64;
    const int col0 = blockIdx.y * 64;
    const int ty = tid >> 4;             // 0..15
    const int tx = tid & 15;             // 0..15
    const int ar = tid >> 2;             // 0..63
    const int ak = (tid & 3) * 4;        // 0,4,8,12
    const int bk = tid >> 4;             // 0..15
    const int bc = (tid & 15) * 4;       // 0..60
    const bool aok = (row0 + ar) < M;
    const float* aptr = A + (size_t)(row0 + ar) * 512;
    float acc[4][4] = {{0.f,0.f,0.f,0.f},{0.f,0.f,0.f,0.f},{0.f,0.f,0.f,0.f},{0.f,0.f,0.f,0.f}};
    for (int k0 = 0; k0 < 512; k0 += 16) {
        float4 av = aok ? *(const float4*)(aptr + k0 + ak) : make_float4(0.f,0.f,0.f,0.f);
        float4 sv = *(const float4*)(aScale + k0 + ak);
        float4 hv = *(const float4*)(aShift + k0 + ak);
        // fused BN+ReLU on A (padding rows only feed C rows >= M, never stored)
        av.x = fmaxf(fmaf(av.x, sv.x, hv.x), 0.f);
        av.y = fmaxf(fmaf(av.y, sv.y, hv.y), 0.f);
        av.z = fmaxf(fmaf(av.z, sv.z, hv.z), 0.f);
        av.w = fmaxf(fmaf(av.w, sv.w, hv.w), 0.f);
        float4 bv = *(const float4*)(B + (size_t)(k0 + bk) * 512 + col0 + bc);
        __syncthreads();
        As[ak + 0][ar] = av.x;
        As[ak + 1][ar] = av.y;
        As[ak + 2][ar] = av.z;
        As[ak + 3][ar] = av.w;
        *(float4*)&Bs[bk][bc] = bv;
        __syncthreads();
#pragma unroll
        for (int kk = 0; kk < 16; ++kk) {
            float2 a01 = *(const float2*)&As[kk][2 * ty];
            float2 a23 = *(const float2*)&As[kk][2 * ty + 32];
            float2 b01 = *(const float2*)&Bs[kk][2 * tx];
            float2 b23 = *(const float2*)&Bs[kk][2 * tx + 32];
            acc[0][0] = fmaf(a01.x, b01.x, acc[0][0]);
            acc[0][1] = fmaf(a01.x, b01.y, acc[0][1]);
            acc[0][2] = fmaf(a01.x, b23.x, acc[0][2]);
            acc[0][3] = fmaf(a01.x, b23.y, acc[0][3]);
            acc[1][0] = fmaf(a01.y, b01.x, acc[1][0]);
            acc[1][1] = fmaf(a01.y, b01.y, acc[1][1]);
            acc[1][2] = fmaf(a01.y, b23.x, acc[1][2]);
            acc[1][3] = fmaf(a01.y, b23.y, acc[1][3]);
            acc[2][0] = fmaf(a23.x, b01.x, acc[2][0]);
            acc[2][1] = fmaf(a23.x, b01.y, acc[2][1]);
            acc[2][2] = fmaf(a23.x, b23.x, acc[2][2]);
            acc[2][3] = fmaf(a23.x, b23.y, acc[2][3]);
            acc[3][0] = fmaf(a23.y, b01.x, acc[3][0]);
            acc[3][1] = fmaf(a23.y, b01.y, acc[3][1]);
            acc[3][2] = fmaf(a23.y, b23.x, acc[3][2]);
            acc[3][3] = fmaf(a23.y, b23.y, acc[3][3]);
        }
    }
    float2 bb01 = *(const float2*)(bias + col0 + 2 * tx);
    float2 bb23 = *(const float2*)(bias + col0 + 2 * tx + 32);
    int rows[4] = {row0 + 2 * ty, row0 + 2 * ty + 1, row0 + 2 * ty + 32, row0 + 2 * ty + 33};
#pragma unroll
    for (int i = 0; i < 4; ++i) {
        int r = rows[i];
        if (r < M) {
            float2 o0 = make_float2(acc[i][0] + bb01.x, acc[i][1] + bb01.y);
            float2 o1 = make_float2(acc[i][2] + bb23.x, acc[i][3] + bb23.y);
            *(float2*)(Cmat + (size_t)r * 512 + col0 + 2 * tx)      = o0;
            *(float2*)(Cmat + (size_t)r * 512 + col0 + 2 * tx + 32) = o1;
        }
    }
}

// ================= CSR build (once per launch; graph shared by both layers) =================

__global__ void hist_kernel(const int* __restrict__ edst, int* __restrict__ deg, int E, int Etot) {
    int e = blockIdx.x * blockDim.x + threadIdx.x;
    if (e >= Etot) return;
    int dst = (e < E) ? edst[e] : (e - E);
    atomicAdd(&deg[dst], 1);
}

// single-workgroup exclusive scan over n (+ total at rowstart[n])
__global__ __launch_bounds__(1024) void scan_kernel(const int* __restrict__ deg,
                                                    int* __restrict__ rowstart, int n) {
    __shared__ int buf[1024];
    __shared__ int carry;
    if (threadIdx.x == 0) carry = 0;
    __syncthreads();
    for (int base = 0; base < n; base += 1024) {
        int i = base + (int)threadIdx.x;
        int v = (i < n) ? deg[i] : 0;
        buf[threadIdx.x] = v;
        __syncthreads();
        for (int off = 1; off < 1024; off <<= 1) {
            int t = (threadIdx.x >= (unsigned)off) ? buf[threadIdx.x - off] : 0;
            __syncthreads();
            buf[threadIdx.x] += t;
            __syncthreads();
        }
        if (i < n) rowstart[i] = carry + buf[threadIdx.x] - v;
        int blocksum = buf[1023];
        __syncthreads();
        if (threadIdx.x == 0) carry += blocksum;
        __syncthreads();
    }
    if (threadIdx.x == 0) rowstart[n] = carry;
}

__global__ void scatter_kernel(const int* __restrict__ esrc, const int* __restrict__ edst,
                               const int* __restrict__ rowstart, int* __restrict__ cursor,
                               int* __restrict__ s_src, int E, int Etot) {
    int e = blockIdx.x * blockDim.x + threadIdx.x;
    if (e >= Etot) return;
    int src = (e < E) ? esrc[e] : (e - E);
    int dst = (e < E) ? edst[e] : (e - E);
    int pos = rowstart[dst] + atomicAdd(&cursor[dst], 1);
    s_src[pos] = src;
}

// ---- fully fused GATv2 edge phase: logits + online softmax + aggregation ----
// one workgroup per dst node; wave h = head h; lane owns 2 consecutive channels.
// per edge: partial dot in-lane -> 64-lane butterfly reduce -> streaming softmax update.
__global__ __launch_bounds__(256) void gat_fused_kernel(
        const float* __restrict__ xl, const float* __restrict__ xr,
        const float* __restrict__ att,
        const int* __restrict__ rowstart, const int* __restrict__ s_src,
        float* __restrict__ out) {
    int node = blockIdx.x;
    int h    = threadIdx.x >> 6;
    int lane = threadIdx.x & 63;
    int beg = rowstart[node];
    int end = rowstart[node + 1];
    int c0 = h * CCH + (lane << 1);
    float2 r2 = *(const float2*)(xr + (size_t)node * HCD + c0);
    float2 a2 = *(const float2*)(att + c0);
    float m = -3.0e38f, den = 0.f, acc0 = 0.f, acc1 = 0.f;
    // 2-stage pipeline: prefetch next edge's xl while reducing current
    float2 l2 = *(const float2*)(xl + (size_t)s_src[beg] * HCD + c0);
    for (int j = beg; j < end; ++j) {
        float2 cur = l2;
        if (j + 1 < end)
            l2 = *(const float2*)(xl + (size_t)s_src[j + 1] * HCD + c0);
        float t0 = cur.x + r2.x; t0 = (t0 > 0.f) ? t0 : SLOPE * t0;
        float t1 = cur.y + r2.y; t1 = (t1 > 0.f) ? t1 : SLOPE * t1;
        float s = fmaf(t0, a2.x, t1 * a2.y);
#pragma unroll
        for (int k = 1; k < 64; k <<= 1) s += __shfl_xor(s, k);
        float mn = fmaxf(m, s);
        float sc = expf(m - mn);     // 0 on first iteration, 1 when max unchanged
        float p  = expf(s - mn);
        den  = fmaf(den,  sc, p);
        acc0 = fmaf(acc0, sc, p * cur.x);
        acc1 = fmaf(acc1, sc, p * cur.y);
        m = mn;
    }
    float inv = 1.0f / (den + 1e-16f);
    *(float2*)(out + (size_t)node * HCD + c0) = make_float2(acc0 * inv, acc1 * inv);
}

// ---- BatchNorm statistics: per-channel sum and sum-of-squares ----
__global__ void bn_stats_kernel(const float* __restrict__ h, float* __restrict__ sum,
                                float* __restrict__ sumsq, int n) {
    int c = blockIdx.y * blockDim.x + threadIdx.x;   // 0..511
    int r0 = blockIdx.x * 128;
    int r1 = min(r0 + 128, n);
    float s = 0.f, s2 = 0.f;
    for (int r = r0; r < r1; ++r) {
        float v = h[(size_t)r * HCD + c];
        s += v;
        s2 = fmaf(v, v, s2);
    }
    atomicAdd(&sum[c], s);
    atomicAdd(&sumsq[c], s2);
}

__global__ void bn_finalize_kernel(const float* __restrict__ sum, const float* __restrict__ sumsq,
                                   const float* __restrict__ g, const float* __restrict__ b,
                                   float* __restrict__ scale, float* __restrict__ shift, int n) {
    int c = threadIdx.x;   // 512
    float inv_n = 1.0f / (float)n;
    float mu = sum[c] * inv_n;
    float var = fmaxf(sumsq[c] * inv_n - mu * mu, 0.0f);
    float sc = g[c] * rsqrtf(var + EPS_BN);
    scale[c] = sc;
    shift[c] = b[c] - mu * sc;
}

// ---- per-graph mean pool with fused BN+ReLU (batch is sorted) ----
__device__ __forceinline__ int lower_bound_i(const int* __restrict__ a, int n, int key) {
    int lo = 0, hi = n;
    while (lo < hi) {
        int mid = (lo + hi) >> 1;
        if (a[mid] < key) lo = mid + 1; else hi = mid;
    }
    return lo;
}

__global__ void pool_bnrelu_kernel(const float* __restrict__ h, const int* __restrict__ batch,
                                   const float* __restrict__ scale, const float* __restrict__ shift,
                                   float* __restrict__ pooled, int n) {
    int g = blockIdx.x;
    int c = threadIdx.x;   // 512
    int start = lower_bound_i(batch, n, g);
    int end   = lower_bound_i(batch, n, g + 1);
    float sc = scale[c], sh = shift[c];
    float s = 0.f;
    for (int r = start; r < end; ++r)
        s += fmaxf(fmaf(h[(size_t)r * HCD + c], sc, sh), 0.f);
    float cnt = (float)max(end - start, 1);
    pooled[(size_t)g * HCD + c] = s / cnt;
}

// ---- MLP head: relu([pooled|gfeat] @ fc1 + b1) @ fc2 + b2 ----
__global__ void head_kernel(const float* __restrict__ pooled, const float* __restrict__ gfeat,
                            const float* __restrict__ fc1w, const float* __restrict__ fc1b,
                            const float* __restrict__ fc2w, const float* __restrict__ fc2b,
                            float* __restrict__ out, int gdim) {
    int g = blockIdx.x;
    int j = threadIdx.x;   // 128
    float acc = fc1b[j];
    const float* prow = pooled + (size_t)g * HCD;
    for (int i = 0; i < HCD; ++i) acc = fmaf(prow[i], fc1w[i * CCH + j], acc);
    const float* grow = gfeat + (size_t)g * gdim;
    for (int i = 0; i < gdim; ++i) acc = fmaf(grow[i], fc1w[(HCD + i) * CCH + j], acc);
    acc = fmaxf(acc, 0.f);
    __shared__ float z[CCH];
    z[j] = acc * fc2w[j];
    __syncthreads();
    for (int s = CCH / 2; s > 0; s >>= 1) {
        if (j < s) z[j] += z[j + s];
        __syncthreads();
    }
    if (j == 0) out[g] = z[0] + fc2b[0];
}

extern "C" void kernel_launch(void* const* d_in, const int* in_sizes, int n_in,
                              void* d_out, int out_size, void* d_ws, size_t ws_size,
                              hipStream_t stream) {
    const float* x     = (const float*)d_in[0];
    const float* gfeat = (const float*)d_in[1];
    const float* W1l   = (const float*)d_in[2];
    const float* b1l   = (const float*)d_in[3];
    const float* W1r   = (const float*)d_in[4];
    const float* b1r   = (const float*)d_in[5];
    const float* att1  = (const float*)d_in[6];
    // d_in[7] = bias1: per-channel constant added right before BatchNorm -> cancels exactly
    const float* W2l   = (const float*)d_in[8];
    const float* b2l   = (const float*)d_in[9];
    const float* W2r   = (const float*)d_in[10];
    const float* b2r   = (const float*)d_in[11];
    const float* att2  = (const float*)d_in[12];
    // d_in[13] = bias2: cancels through BN
    const float* bn1_g = (const float*)d_in[14];
    const float* bn1_b = (const float*)d_in[15];
    const float* bn2_g = (const float*)d_in[16];
    const float* bn2_b = (const float*)d_in[17];
    const float* fc1w  = (const float*)d_in[18];
    const float* fc1b  = (const float*)d_in[19];
    const float* fc2w  = (const float*)d_in[20];
    const float* fc2b  = (const float*)d_in[21];
    const int* eidx    = (const int*)d_in[22];
    const int* batch   = (const int*)d_in[23];

    const int n    = in_sizes[0] / 9;
    const int E    = in_sizes[22] / 2;
    const int Etot = E + n;
    const int b    = out_size;
    const int gdim = in_sizes[1] / b;
    const int* esrc = eidx;
    const int* edst = eidx + E;

    float* ws = (float*)d_ws;
    size_t nHC = (size_t)n * HCD;
    float* xl      = ws;
    float* xr      = xl + nHC;
    float* hbuf    = xr + nHC;
    int* deg       = (int*)(hbuf + nHC);     // n
    int* rowstart  = deg + n;                // n+1
    int* cursor    = rowstart + n + 1;       // n
    int* s_src     = cursor + n;             // Etot
    float* bnsum   = (float*)(s_src + Etot); // 512
    float* bnsumsq = bnsum + HCD;            // 512
    float* bnscale = bnsumsq + HCD;          // 512
    float* bnshift = bnscale + HCD;          // 512
    float* pooled  = bnshift + HCD;          // b*512

    const int BLK = 256;
    const int linBlocks  = (int)((nHC + BLK - 1) / BLK);
    const int eBlocks    = (Etot + BLK - 1) / BLK;
    const int bnxBlocks  = (n + 127) / 128;
    dim3 gemmGrid((n + 63) / 64, 512 / 64);

    // ---------------- CSR build (shared by both layers) ----------------
    hipMemsetAsync(deg, 0, (size_t)(2 * n + 1) * sizeof(int), stream);  // deg + rowstart head
    hipMemsetAsync(cursor, 0, (size_t)n * sizeof(int), stream);
    hist_kernel<<<eBlocks, BLK, 0, stream>>>(edst, deg, E, Etot);
    scan_kernel<<<1, 1024, 0, stream>>>(deg, rowstart, n);
    scatter_kernel<<<eBlocks, BLK, 0, stream>>>(esrc, edst, rowstart, cursor, s_src, E, Etot);

    // ---------------- layer 1 ----------------
    lin1_kernel<<<linBlocks, BLK, 0, stream>>>(x, W1l, b1l, W1r, b1r, xl, xr, n);
    gat_fused_kernel<<<n, 256, 0, stream>>>(xl, xr, att1, rowstart, s_src, hbuf);
    hipMemsetAsync(bnsum, 0, HCD * 2 * sizeof(float), stream);
    bn_stats_kernel<<<dim3(bnxBlocks, 2), BLK, 0, stream>>>(hbuf, bnsum, bnsumsq, n);
    bn_finalize_kernel<<<1, HCD, 0, stream>>>(bnsum, bnsumsq, bn1_g, bn1_b, bnscale, bnshift, n);

    // ---------------- layer 2 (BN1+ReLU fused into GEMM A-stage) ----------------
    gemm512_bnrelu_kernel<<<gemmGrid, BLK, 0, stream>>>(hbuf, W2l, bnscale, bnshift, b2l, xl, n);
    gemm512_bnrelu_kernel<<<gemmGrid, BLK, 0, stream>>>(hbuf, W2r, bnscale, bnshift, b2r, xr, n);
    gat_fused_kernel<<<n, 256, 0, stream>>>(xl, xr, att2, rowstart, s_src, hbuf);
    hipMemsetAsync(bnsum, 0, HCD * 2 * sizeof(float), stream);
    bn_stats_kernel<<<dim3(bnxBlocks, 2), BLK, 0, stream>>>(hbuf, bnsum, bnsumsq, n);
    bn_finalize_kernel<<<1, HCD, 0, stream>>>(bnsum, bnsumsq, bn2_g, bn2_b, bnscale, bnshift, n);

    // ---------------- readout (BN2+ReLU fused into pool) ----------------
    pool_bnrelu_kernel<<<b, HCD, 0, stream>>>(hbuf, batch, bnscale, bnshift, pooled, n);
    head_kernel<<<b, CCH, 0, stream>>>(pooled, gfeat, fc1w, fc1b, fc2w, fc2b, (float*)d_out, gdim);
}

// Round 7
// 1181.835 us; speedup vs baseline: 4.1199x; 1.0698x over previous
//
#include <hip/hip_runtime.h>
#include <math.h>

#define NHEAD 4
#define CCH 128
#define HCD 512
#define SLOPE 0.2f
#define EPS_BN 1e-5f

// ---- layer 1 node transforms: x[N,9] @ W[9,512] + b, both l and r ----
__global__ void lin1_kernel(const float* __restrict__ x,
                            const float* __restrict__ Wl, const float* __restrict__ bl,
                            const float* __restrict__ Wr, const float* __restrict__ br,
                            float* __restrict__ xl, float* __restrict__ xr, int n) {
    int gid = blockIdx.x * blockDim.x + threadIdx.x;
    if (gid >= n * HCD) return;
    int node = gid >> 9;
    int c = gid & (HCD - 1);
    const float* xrow = x + node * 9;
    float a = bl[c], bz = br[c];
#pragma unroll
    for (int k = 0; k < 9; ++k) {
        float xv = xrow[k];
        a  = fmaf(xv, Wl[k * HCD + c], a);
        bz = fmaf(xv, Wr[k * HCD + c], bz);
    }
    xl[gid] = a;
    xr[gid] = bz;
}

// ---- fp32 tiled GEMM: C[M,512] = A[M,512] @ B[512,512] + bias ----
// reg double-buffered (prefetch k0+16 during compute); As padded to 66 so the
// transpose-write hits 4 distinct banks (ak*66 mod 32 = {0,8,16,24}).
__global__ __launch_bounds__(256) void gemm512_kernel(
        const float* __restrict__ A, const float* __restrict__ B,
        const float* __restrict__ bias, float* __restrict__ Cmat, int M) {
    __shared__ float As[16][66];   // As[k][m], padded
    __shared__ float Bs[16][64];   // Bs[k][n]
    const int tid  = threadIdx.x;
    const int row0 = blockIdx.x * 64;
    const int col0 = blockIdx.y * 64;
    const int tm = (tid >> 4) * 4;       // 0..60
    const int tn = (tid & 15) * 4;       // 0..60
    const int ar = tid >> 2;             // 0..63
    const int ak = (tid & 3) * 4;        // 0,4,8,12
    const int bk = tid >> 4;             // 0..15
    const int bc = (tid & 15) * 4;       // 0..60
    const bool aok = (row0 + ar) < M;
    const float* aptr = A + (size_t)(row0 + ar) * 512;
    float4 av = aok ? *(const float4*)(aptr + ak) : make_float4(0.f,0.f,0.f,0.f);
    float4 bv = *(const float4*)(B + (size_t)bk * 512 + col0 + bc);
    float acc[4][4] = {{0.f,0.f,0.f,0.f},{0.f,0.f,0.f,0.f},{0.f,0.f,0.f,0.f},{0.f,0.f,0.f,0.f}};
    for (int k0 = 0; k0 < 512; k0 += 16) {
        As[ak + 0][ar] = av.x;
        As[ak + 1][ar] = av.y;
        As[ak + 2][ar] = av.z;
        As[ak + 3][ar] = av.w;
        *(float4*)&Bs[bk][bc] = bv;
        __syncthreads();
        if (k0 + 16 < 512) {   // prefetch next tile; latency hides under the 16-step FMA block
            av = aok ? *(const float4*)(aptr + k0 + 16 + ak) : make_float4(0.f,0.f,0.f,0.f);
            bv = *(const float4*)(B + (size_t)(k0 + 16 + bk) * 512 + col0 + bc);
        }
#pragma unroll
        for (int kk = 0; kk < 16; ++kk) {
            float4 a4 = *(const float4*)&As[kk][tm];
            float4 b4 = *(const float4*)&Bs[kk][tn];
            acc[0][0] = fmaf(a4.x, b4.x, acc[0][0]);
            acc[0][1] = fmaf(a4.x, b4.y, acc[0][1]);
            acc[0][2] = fmaf(a4.x, b4.z, acc[0][2]);
            acc[0][3] = fmaf(a4.x, b4.w, acc[0][3]);
            acc[1][0] = fmaf(a4.y, b4.x, acc[1][0]);
            acc[1][1] = fmaf(a4.y, b4.y, acc[1][1]);
            acc[1][2] = fmaf(a4.y, b4.z, acc[1][2]);
            acc[1][3] = fmaf(a4.y, b4.w, acc[1][3]);
            acc[2][0] = fmaf(a4.z, b4.x, acc[2][0]);
            acc[2][1] = fmaf(a4.z, b4.y, acc[2][1]);
            acc[2][2] = fmaf(a4.z, b4.z, acc[2][2]);
            acc[2][3] = fmaf(a4.z, b4.w, acc[2][3]);
            acc[3][0] = fmaf(a4.w, b4.x, acc[3][0]);
            acc[3][1] = fmaf(a4.w, b4.y, acc[3][1]);
            acc[3][2] = fmaf(a4.w, b4.z, acc[3][2]);
            acc[3][3] = fmaf(a4.w, b4.w, acc[3][3]);
        }
        __syncthreads();
    }
    float4 bb = *(const float4*)(bias + col0 + tn);
#pragma unroll
    for (int i = 0; i < 4; ++i) {
        int r = row0 + tm + i;
        if (r < M) {
            float4 o;
            o.x = acc[i][0] + bb.x;
            o.y = acc[i][1] + bb.y;
            o.z = acc[i][2] + bb.z;
            o.w = acc[i][3] + bb.w;
            *(float4*)(Cmat + (size_t)r * 512 + col0 + tn) = o;
        }
    }
}

// ================= CSR build (once per launch; graph shared by both layers) =================

__global__ void hist_kernel(const int* __restrict__ edst, int* __restrict__ deg, int E, int Etot) {
    int e = blockIdx.x * blockDim.x + threadIdx.x;
    if (e >= Etot) return;
    int dst = (e < E) ? edst[e] : (e - E);
    atomicAdd(&deg[dst], 1);
}

// single-workgroup exclusive scan over n (+ total at rowstart[n])
__global__ __launch_bounds__(1024) void scan_kernel(const int* __restrict__ deg,
                                                    int* __restrict__ rowstart, int n) {
    __shared__ int buf[1024];
    __shared__ int carry;
    if (threadIdx.x == 0) carry = 0;
    __syncthreads();
    for (int base = 0; base < n; base += 1024) {
        int i = base + (int)threadIdx.x;
        int v = (i < n) ? deg[i] : 0;
        buf[threadIdx.x] = v;
        __syncthreads();
        for (int off = 1; off < 1024; off <<= 1) {
            int t = (threadIdx.x >= (unsigned)off) ? buf[threadIdx.x - off] : 0;
            __syncthreads();
            buf[threadIdx.x] += t;
            __syncthreads();
        }
        if (i < n) rowstart[i] = carry + buf[threadIdx.x] - v;
        int blocksum = buf[1023];
        __syncthreads();
        if (threadIdx.x == 0) carry += blocksum;
        __syncthreads();
    }
    if (threadIdx.x == 0) rowstart[n] = carry;
}

__global__ void scatter_kernel(const int* __restrict__ esrc, const int* __restrict__ edst,
                               const int* __restrict__ rowstart, int* __restrict__ cursor,
                               int* __restrict__ s_src, int E, int Etot) {
    int e = blockIdx.x * blockDim.x + threadIdx.x;
    if (e >= Etot) return;
    int src = (e < E) ? esrc[e] : (e - E);
    int dst = (e < E) ? edst[e] : (e - E);
    int pos = rowstart[dst] + atomicAdd(&cursor[dst], 1);
    s_src[pos] = src;
}

// ---- fully fused GATv2 edge phase: logits + online softmax + aggregation ----
// one workgroup per dst node; wave h = head h; lane owns 2 consecutive channels.
__global__ __launch_bounds__(256) void gat_fused_kernel(
        const float* __restrict__ xl, const float* __restrict__ xr,
        const float* __restrict__ att,
        const int* __restrict__ rowstart, const int* __restrict__ s_src,
        float* __restrict__ out) {
    int node = blockIdx.x;
    int h    = threadIdx.x >> 6;
    int lane = threadIdx.x & 63;
    int beg = rowstart[node];
    int end = rowstart[node + 1];
    int c0 = h * CCH + (lane << 1);
    float2 r2 = *(const float2*)(xr + (size_t)node * HCD + c0);
    float2 a2 = *(const float2*)(att + c0);
    float m = -3.0e38f, den = 0.f, acc0 = 0.f, acc1 = 0.f;
    // 2-stage pipeline: prefetch next edge's xl while reducing current
    float2 l2 = *(const float2*)(xl + (size_t)s_src[beg] * HCD + c0);
    for (int j = beg; j < end; ++j) {
        float2 cur = l2;
        if (j + 1 < end)
            l2 = *(const float2*)(xl + (size_t)s_src[j + 1] * HCD + c0);
        float t0 = cur.x + r2.x; t0 = (t0 > 0.f) ? t0 : SLOPE * t0;
        float t1 = cur.y + r2.y; t1 = (t1 > 0.f) ? t1 : SLOPE * t1;
        float s = fmaf(t0, a2.x, t1 * a2.y);
#pragma unroll
        for (int k = 1; k < 64; k <<= 1) s += __shfl_xor(s, k);
        float mn = fmaxf(m, s);
        float sc = expf(m - mn);     // 0 on first iteration, 1 when max unchanged
        float p  = expf(s - mn);
        den  = fmaf(den,  sc, p);
        acc0 = fmaf(acc0, sc, p * cur.x);
        acc1 = fmaf(acc1, sc, p * cur.y);
        m = mn;
    }
    float inv = 1.0f / (den + 1e-16f);
    *(float2*)(out + (size_t)node * HCD + c0) = make_float2(acc0 * inv, acc1 * inv);
}

// ---- BatchNorm statistics: per-channel sum and sum-of-squares ----
__global__ void bn_stats_kernel(const float* __restrict__ h, float* __restrict__ sum,
                                float* __restrict__ sumsq, int n) {
    int c = blockIdx.y * blockDim.x + threadIdx.x;   // 0..511
    int r0 = blockIdx.x * 128;
    int r1 = min(r0 + 128, n);
    float s = 0.f, s2 = 0.f;
    for (int r = r0; r < r1; ++r) {
        float v = h[(size_t)r * HCD + c];
        s += v;
        s2 = fmaf(v, v, s2);
    }
    atomicAdd(&sum[c], s);
    atomicAdd(&sumsq[c], s2);
}

__global__ void bn_finalize_kernel(const float* __restrict__ sum, const float* __restrict__ sumsq,
                                   const float* __restrict__ g, const float* __restrict__ b,
                                   float* __restrict__ scale, float* __restrict__ shift, int n) {
    int c = threadIdx.x;   // 512
    float inv_n = 1.0f / (float)n;
    float mu = sum[c] * inv_n;
    float var = fmaxf(sumsq[c] * inv_n - mu * mu, 0.0f);
    float sc = g[c] * rsqrtf(var + EPS_BN);
    scale[c] = sc;
    shift[c] = b[c] - mu * sc;
}

__global__ void bn_apply_relu_kernel(float* __restrict__ h, const float* __restrict__ scale,
                                     const float* __restrict__ shift, int total4) {
    int gid = blockIdx.x * blockDim.x + threadIdx.x;
    if (gid >= total4) return;
    int c4 = gid & 127;
    float4 v = ((float4*)h)[gid];
    float4 sc = ((const float4*)scale)[c4];
    float4 sh = ((const float4*)shift)[c4];
    v.x = fmaxf(fmaf(v.x, sc.x, sh.x), 0.f);
    v.y = fmaxf(fmaf(v.y, sc.y, sh.y), 0.f);
    v.z = fmaxf(fmaf(v.z, sc.z, sh.z), 0.f);
    v.w = fmaxf(fmaf(v.w, sc.w, sh.w), 0.f);
    ((float4*)h)[gid] = v;
}

// ---- per-graph mean pool with fused BN+ReLU (batch is sorted) ----
__device__ __forceinline__ int lower_bound_i(const int* __restrict__ a, int n, int key) {
    int lo = 0, hi = n;
    while (lo < hi) {
        int mid = (lo + hi) >> 1;
        if (a[mid] < key) lo = mid + 1; else hi = mid;
    }
    return lo;
}

__global__ void pool_bnrelu_kernel(const float* __restrict__ h, const int* __restrict__ batch,
                                   const float* __restrict__ scale, const float* __restrict__ shift,
                                   float* __restrict__ pooled, int n) {
    int g = blockIdx.x;
    int c = threadIdx.x;   // 512
    int start = lower_bound_i(batch, n, g);
    int end   = lower_bound_i(batch, n, g + 1);
    float sc = scale[c], sh = shift[c];
    float s = 0.f;
    for (int r = start; r < end; ++r)
        s += fmaxf(fmaf(h[(size_t)r * HCD + c], sc, sh), 0.f);
    float cnt = (float)max(end - start, 1);
    pooled[(size_t)g * HCD + c] = s / cnt;
}

// ---- MLP head: relu([pooled|gfeat] @ fc1 + b1) @ fc2 + b2 ----
__global__ void head_kernel(const float* __restrict__ pooled, const float* __restrict__ gfeat,
                            const float* __restrict__ fc1w, const float* __restrict__ fc1b,
                            const float* __restrict__ fc2w, const float* __restrict__ fc2b,
                            float* __restrict__ out, int gdim) {
    int g = blockIdx.x;
    int j = threadIdx.x;   // 128
    float acc = fc1b[j];
    const float* prow = pooled + (size_t)g * HCD;
    for (int i = 0; i < HCD; ++i) acc = fmaf(prow[i], fc1w[i * CCH + j], acc);
    const float* grow = gfeat + (size_t)g * gdim;
    for (int i = 0; i < gdim; ++i) acc = fmaf(grow[i], fc1w[(HCD + i) * CCH + j], acc);
    acc = fmaxf(acc, 0.f);
    __shared__ float z[CCH];
    z[j] = acc * fc2w[j];
    __syncthreads();
    for (int s = CCH / 2; s > 0; s >>= 1) {
        if (j < s) z[j] += z[j + s];
        __syncthreads();
    }
    if (j == 0) out[g] = z[0] + fc2b[0];
}

extern "C" void kernel_launch(void* const* d_in, const int* in_sizes, int n_in,
                              void* d_out, int out_size, void* d_ws, size_t ws_size,
                              hipStream_t stream) {
    const float* x     = (const float*)d_in[0];
    const float* gfeat = (const float*)d_in[1];
    const float* W1l   = (const float*)d_in[2];
    const float* b1l   = (const float*)d_in[3];
    const float* W1r   = (const float*)d_in[4];
    const float* b1r   = (const float*)d_in[5];
    const float* att1  = (const float*)d_in[6];
    // d_in[7] = bias1: per-channel constant added right before BatchNorm -> cancels exactly
    const float* W2l   = (const float*)d_in[8];
    const float* b2l   = (const float*)d_in[9];
    const float* W2r   = (const float*)d_in[10];
    const float* b2r   = (const float*)d_in[11];
    const float* att2  = (const float*)d_in[12];
    // d_in[13] = bias2: cancels through BN
    const float* bn1_g = (const float*)d_in[14];
    const float* bn1_b = (const float*)d_in[15];
    const float* bn2_g = (const float*)d_in[16];
    const float* bn2_b = (const float*)d_in[17];
    const float* fc1w  = (const float*)d_in[18];
    const float* fc1b  = (const float*)d_in[19];
    const float* fc2w  = (const float*)d_in[20];
    const float* fc2b  = (const float*)d_in[21];
    const int* eidx    = (const int*)d_in[22];
    const int* batch   = (const int*)d_in[23];

    const int n    = in_sizes[0] / 9;
    const int E    = in_sizes[22] / 2;
    const int Etot = E + n;
    const int b    = out_size;
    const int gdim = in_sizes[1] / b;
    const int* esrc = eidx;
    const int* edst = eidx + E;

    float* ws = (float*)d_ws;
    size_t nHC = (size_t)n * HCD;
    float* xl      = ws;
    float* xr      = xl + nHC;
    float* hbuf    = xr + nHC;
    int* deg       = (int*)(hbuf + nHC);     // n
    int* rowstart  = deg + n;                // n+1
    int* cursor    = rowstart + n + 1;       // n
    int* s_src     = cursor + n;             // Etot
    float* bnsum   = (float*)(s_src + Etot); // 512
    float* bnsumsq = bnsum + HCD;            // 512
    float* bnscale = bnsumsq + HCD;          // 512
    float* bnshift = bnscale + HCD;          // 512
    float* pooled  = bnshift + HCD;          // b*512

    const int BLK = 256;
    const int linBlocks  = (int)((nHC + BLK - 1) / BLK);
    const int eBlocks    = (Etot + BLK - 1) / BLK;
    const int bnxBlocks  = (n + 127) / 128;
    const int bnaBlocks  = (int)((nHC / 4 + BLK - 1) / BLK);
    dim3 gemmGrid((n + 63) / 64, 512 / 64);

    // ---------------- CSR build (shared by both layers) ----------------
    hipMemsetAsync(deg, 0, (size_t)(2 * n + 1) * sizeof(int), stream);  // deg + rowstart head
    hipMemsetAsync(cursor, 0, (size_t)n * sizeof(int), stream);
    hist_kernel<<<eBlocks, BLK, 0, stream>>>(edst, deg, E, Etot);
    scan_kernel<<<1, 1024, 0, stream>>>(deg, rowstart, n);
    scatter_kernel<<<eBlocks, BLK, 0, stream>>>(esrc, edst, rowstart, cursor, s_src, E, Etot);

    // ---------------- layer 1 ----------------
    lin1_kernel<<<linBlocks, BLK, 0, stream>>>(x, W1l, b1l, W1r, b1r, xl, xr, n);
    gat_fused_kernel<<<n, 256, 0, stream>>>(xl, xr, att1, rowstart, s_src, hbuf);
    hipMemsetAsync(bnsum, 0, HCD * 2 * sizeof(float), stream);
    bn_stats_kernel<<<dim3(bnxBlocks, 2), BLK, 0, stream>>>(hbuf, bnsum, bnsumsq, n);
    bn_finalize_kernel<<<1, HCD, 0, stream>>>(bnsum, bnsumsq, bn1_g, bn1_b, bnscale, bnshift, n);
    bn_apply_relu_kernel<<<bnaBlocks, BLK, 0, stream>>>(hbuf, bnscale, bnshift, (int)(nHC / 4));

    // ---------------- layer 2 ----------------
    gemm512_kernel<<<gemmGrid, BLK, 0, stream>>>(hbuf, W2l, b2l, xl, n);
    gemm512_kernel<<<gemmGrid, BLK, 0, stream>>>(hbuf, W2r, b2r, xr, n);
    gat_fused_kernel<<<n, 256, 0, stream>>>(xl, xr, att2, rowstart, s_src, hbuf);
    hipMemsetAsync(bnsum, 0, HCD * 2 * sizeof(float), stream);
    bn_stats_kernel<<<dim3(bnxBlocks, 2), BLK, 0, stream>>>(hbuf, bnsum, bnsumsq, n);
    bn_finalize_kernel<<<1, HCD, 0, stream>>>(bnsum, bnsumsq, bn2_g, bn2_b, bnscale, bnshift, n);

    // ---------------- readout (BN2+ReLU fused into pool) ----------------
    pool_bnrelu_kernel<<<b, HCD, 0, stream>>>(hbuf, batch, bnscale, bnshift, pooled, n);
    head_kernel<<<b, CCH, 0, stream>>>(pooled, gfeat, fc1w, fc1b, fc2w, fc2b, (float*)d_out, gdim);
}

// Round 8
// 1091.936 us; speedup vs baseline: 4.4591x; 1.0823x over previous
//
#include <hip/hip_runtime.h>
#include <math.h>

#define NHEAD 4
#define CCH 128
#define HCD 512
#define SLOPE 0.2f
#define EPS_BN 1e-5f

// ---- layer 1 node transforms: x[N,9] @ W[9,512] + b, both l and r ----
__global__ void lin1_kernel(const float* __restrict__ x,
                            const float* __restrict__ Wl, const float* __restrict__ bl,
                            const float* __restrict__ Wr, const float* __restrict__ br,
                            float* __restrict__ xl, float* __restrict__ xr, int n) {
    int gid = blockIdx.x * blockDim.x + threadIdx.x;
    if (gid >= n * HCD) return;
    int node = gid >> 9;
    int c = gid & (HCD - 1);
    const float* xrow = x + node * 9;
    float a = bl[c], bz = br[c];
#pragma unroll
    for (int k = 0; k < 9; ++k) {
        float xv = xrow[k];
        a  = fmaf(xv, Wl[k * HCD + c], a);
        bz = fmaf(xv, Wr[k * HCD + c], bz);
    }
    xl[gid] = a;
    xr[gid] = bz;
}

// ---- dual fp32 GEMM, 128x128 tile, 8x8 micro-tile, fused BN+ReLU on A ----
//  y<4 : outL = relu(A*sc+sh) @ Bl + biasl   (cols (y&3)*128)
//  y>=4: outR = relu(A*sc+sh) @ Br + biasr
__global__ __launch_bounds__(256) void gemm_dual_kernel(
        const float* __restrict__ A,
        const float* __restrict__ Bl, const float* __restrict__ biasl,
        const float* __restrict__ Br, const float* __restrict__ biasr,
        const float* __restrict__ aScale, const float* __restrict__ aShift,
        float* __restrict__ outL, float* __restrict__ outR, int M) {
    __shared__ float As[16][130];   // As[k][m], padded (stores 2-way max)
    __shared__ float Bs[16][132];   // Bs[k][n], padded
    const float* Bmat  = (blockIdx.y < 4) ? Bl : Br;
    const float* bias  = (blockIdx.y < 4) ? biasl : biasr;
    float*       Cout  = (blockIdx.y < 4) ? outL : outR;
    const int col0 = (blockIdx.y & 3) * 128;
    const int row0 = blockIdx.x * 128;
    const int tid  = threadIdx.x;
    // staging coords
    const int ar = tid >> 2;             // 0..63 (A row within pass)
    const int ck = (tid & 3) * 4;        // 0,4,8,12 (A k-col)
    const int bkr = tid >> 5;            // 0..7 (B k-row within pass)
    const int bcc = (tid & 31) * 4;      // 0..124 (B col)
    // micro-tile coords
    const int tx4 = (tid & 15) * 4;      // 0..60
    const int ty4 = (tid >> 4) * 4;      // 0..60
    const bool aok0 = (row0 + ar) < M;
    const bool aok1 = (row0 + 64 + ar) < M;
    const float* aptr0 = A + (size_t)(row0 + ar) * 512 + ck;
    const float* aptr1 = A + (size_t)(row0 + 64 + ar) * 512 + ck;

    float4 av0, av1, bv0, bv1, sv, hv;
    sv = *(const float4*)(aScale + ck);
    hv = *(const float4*)(aShift + ck);
    av0 = aok0 ? *(const float4*)(aptr0) : make_float4(0.f,0.f,0.f,0.f);
    av1 = aok1 ? *(const float4*)(aptr1) : make_float4(0.f,0.f,0.f,0.f);
    bv0 = *(const float4*)(Bmat + (size_t)(bkr    ) * 512 + col0 + bcc);
    bv1 = *(const float4*)(Bmat + (size_t)(bkr + 8) * 512 + col0 + bcc);
    // fused BN+ReLU (padding rows produce garbage but never stored)
    av0.x = fmaxf(fmaf(av0.x, sv.x, hv.x), 0.f); av0.y = fmaxf(fmaf(av0.y, sv.y, hv.y), 0.f);
    av0.z = fmaxf(fmaf(av0.z, sv.z, hv.z), 0.f); av0.w = fmaxf(fmaf(av0.w, sv.w, hv.w), 0.f);
    av1.x = fmaxf(fmaf(av1.x, sv.x, hv.x), 0.f); av1.y = fmaxf(fmaf(av1.y, sv.y, hv.y), 0.f);
    av1.z = fmaxf(fmaf(av1.z, sv.z, hv.z), 0.f); av1.w = fmaxf(fmaf(av1.w, sv.w, hv.w), 0.f);

    float acc[8][8];
#pragma unroll
    for (int i = 0; i < 8; ++i)
#pragma unroll
        for (int j = 0; j < 8; ++j) acc[i][j] = 0.f;

    for (int k0 = 0; k0 < 512; k0 += 16) {
        As[ck + 0][ar]      = av0.x; As[ck + 1][ar]      = av0.y;
        As[ck + 2][ar]      = av0.z; As[ck + 3][ar]      = av0.w;
        As[ck + 0][ar + 64] = av1.x; As[ck + 1][ar + 64] = av1.y;
        As[ck + 2][ar + 64] = av1.z; As[ck + 3][ar + 64] = av1.w;
        *(float4*)&Bs[bkr][bcc]     = bv0;
        *(float4*)&Bs[bkr + 8][bcc] = bv1;
        __syncthreads();
        if (k0 + 16 < 512) {   // prefetch next k-tile; hides under the FMA block
            int kn = k0 + 16;
            sv = *(const float4*)(aScale + kn + ck);
            hv = *(const float4*)(aShift + kn + ck);
            av0 = aok0 ? *(const float4*)(aptr0 + kn) : make_float4(0.f,0.f,0.f,0.f);
            av1 = aok1 ? *(const float4*)(aptr1 + kn) : make_float4(0.f,0.f,0.f,0.f);
            bv0 = *(const float4*)(Bmat + (size_t)(kn + bkr    ) * 512 + col0 + bcc);
            bv1 = *(const float4*)(Bmat + (size_t)(kn + bkr + 8) * 512 + col0 + bcc);
            av0.x = fmaxf(fmaf(av0.x, sv.x, hv.x), 0.f); av0.y = fmaxf(fmaf(av0.y, sv.y, hv.y), 0.f);
            av0.z = fmaxf(fmaf(av0.z, sv.z, hv.z), 0.f); av0.w = fmaxf(fmaf(av0.w, sv.w, hv.w), 0.f);
            av1.x = fmaxf(fmaf(av1.x, sv.x, hv.x), 0.f); av1.y = fmaxf(fmaf(av1.y, sv.y, hv.y), 0.f);
            av1.z = fmaxf(fmaf(av1.z, sv.z, hv.z), 0.f); av1.w = fmaxf(fmaf(av1.w, sv.w, hv.w), 0.f);
        }
#pragma unroll
        for (int kk = 0; kk < 16; ++kk) {
            float4 a0 = *(const float4*)&As[kk][ty4];
            float4 a1 = *(const float4*)&As[kk][ty4 + 64];
            float4 b0 = *(const float4*)&Bs[kk][tx4];
            float4 b1 = *(const float4*)&Bs[kk][tx4 + 64];
            float am[8] = {a0.x,a0.y,a0.z,a0.w,a1.x,a1.y,a1.z,a1.w};
            float bm[8] = {b0.x,b0.y,b0.z,b0.w,b1.x,b1.y,b1.z,b1.w};
#pragma unroll
            for (int i = 0; i < 8; ++i)
#pragma unroll
                for (int j = 0; j < 8; ++j)
                    acc[i][j] = fmaf(am[i], bm[j], acc[i][j]);
        }
        __syncthreads();
    }
    float4 bb0 = *(const float4*)(bias + col0 + tx4);
    float4 bb1 = *(const float4*)(bias + col0 + tx4 + 64);
#pragma unroll
    for (int i = 0; i < 8; ++i) {
        int r = row0 + ((i < 4) ? (ty4 + i) : (64 + ty4 + i - 4));
        if (r < M) {
            float4 o0 = make_float4(acc[i][0] + bb0.x, acc[i][1] + bb0.y,
                                    acc[i][2] + bb0.z, acc[i][3] + bb0.w);
            float4 o1 = make_float4(acc[i][4] + bb1.x, acc[i][5] + bb1.y,
                                    acc[i][6] + bb1.z, acc[i][7] + bb1.w);
            *(float4*)(Cout + (size_t)r * 512 + col0 + tx4)      = o0;
            *(float4*)(Cout + (size_t)r * 512 + col0 + tx4 + 64) = o1;
        }
    }
}

// ================= CSR build (once per launch; graph shared by both layers) =================

__global__ void hist_kernel(const int* __restrict__ edst, int* __restrict__ deg, int E, int Etot) {
    int e = blockIdx.x * blockDim.x + threadIdx.x;
    if (e >= Etot) return;
    int dst = (e < E) ? edst[e] : (e - E);
    atomicAdd(&deg[dst], 1);
}

// single-workgroup exclusive scan over n (+ total at rowstart[n])
__global__ __launch_bounds__(1024) void scan_kernel(const int* __restrict__ deg,
                                                    int* __restrict__ rowstart, int n) {
    __shared__ int buf[1024];
    __shared__ int carry;
    if (threadIdx.x == 0) carry = 0;
    __syncthreads();
    for (int base = 0; base < n; base += 1024) {
        int i = base + (int)threadIdx.x;
        int v = (i < n) ? deg[i] : 0;
        buf[threadIdx.x] = v;
        __syncthreads();
        for (int off = 1; off < 1024; off <<= 1) {
            int t = (threadIdx.x >= (unsigned)off) ? buf[threadIdx.x - off] : 0;
            __syncthreads();
            buf[threadIdx.x] += t;
            __syncthreads();
        }
        if (i < n) rowstart[i] = carry + buf[threadIdx.x] - v;
        int blocksum = buf[1023];
        __syncthreads();
        if (threadIdx.x == 0) carry += blocksum;
        __syncthreads();
    }
    if (threadIdx.x == 0) rowstart[n] = carry;
}

__global__ void scatter_kernel(const int* __restrict__ esrc, const int* __restrict__ edst,
                               const int* __restrict__ rowstart, int* __restrict__ cursor,
                               int* __restrict__ s_src, int E, int Etot) {
    int e = blockIdx.x * blockDim.x + threadIdx.x;
    if (e >= Etot) return;
    int src = (e < E) ? esrc[e] : (e - E);
    int dst = (e < E) ? edst[e] : (e - E);
    int pos = rowstart[dst] + atomicAdd(&cursor[dst], 1);
    s_src[pos] = src;
}

// ---- fully fused GATv2 edge phase: logits + online softmax + aggregation ----
// one workgroup per dst node; wave h = head h; lane owns 2 consecutive channels.
// 2-edge unrolled: two independent shuffle-reduce chains interleave (ILP),
// one exact pairwise online-softmax update per pair.
__global__ __launch_bounds__(256) void gat_fused_kernel(
        const float* __restrict__ xl, const float* __restrict__ xr,
        const float* __restrict__ att,
        const int* __restrict__ rowstart, const int* __restrict__ s_src,
        float* __restrict__ out) {
    int node = blockIdx.x;
    int h    = threadIdx.x >> 6;
    int lane = threadIdx.x & 63;
    int beg = rowstart[node];
    int end = rowstart[node + 1];
    int c0 = h * CCH + (lane << 1);
    float2 r2 = *(const float2*)(xr + (size_t)node * HCD + c0);
    float2 a2 = *(const float2*)(att + c0);
    float m = -3.0e38f, den = 0.f, acc0 = 0.f, acc1 = 0.f;

    int j = beg;
    float2 lA = *(const float2*)(xl + (size_t)s_src[j] * HCD + c0);   // deg >= 1 (self-loop)
    float2 lB;
    if (j + 1 < end) lB = *(const float2*)(xl + (size_t)s_src[j + 1] * HCD + c0);

    while (j + 1 < end) {
        float2 A = lA, B = lB;
        if (j + 2 < end) lA = *(const float2*)(xl + (size_t)s_src[j + 2] * HCD + c0);
        if (j + 3 < end) lB = *(const float2*)(xl + (size_t)s_src[j + 3] * HCD + c0);
        float ta0 = A.x + r2.x; ta0 = (ta0 > 0.f) ? ta0 : SLOPE * ta0;
        float ta1 = A.y + r2.y; ta1 = (ta1 > 0.f) ? ta1 : SLOPE * ta1;
        float tb0 = B.x + r2.x; tb0 = (tb0 > 0.f) ? tb0 : SLOPE * tb0;
        float tb1 = B.y + r2.y; tb1 = (tb1 > 0.f) ? tb1 : SLOPE * tb1;
        float sA = fmaf(ta0, a2.x, ta1 * a2.y);
        float sB = fmaf(tb0, a2.x, tb1 * a2.y);
#pragma unroll
        for (int k = 1; k < 64; k <<= 1) {
            sA += __shfl_xor(sA, k);
            sB += __shfl_xor(sB, k);
        }
        float mn = fmaxf(m, fmaxf(sA, sB));
        float sc = expf(m - mn);
        float pA = expf(sA - mn);
        float pB = expf(sB - mn);
        den  = fmaf(den,  sc, pA + pB);
        acc0 = fmaf(acc0, sc, fmaf(pA, A.x, pB * B.x));
        acc1 = fmaf(acc1, sc, fmaf(pA, A.y, pB * B.y));
        m = mn;
        j += 2;
    }
    if (j < end) {   // odd tail
        float2 A = lA;
        float ta0 = A.x + r2.x; ta0 = (ta0 > 0.f) ? ta0 : SLOPE * ta0;
        float ta1 = A.y + r2.y; ta1 = (ta1 > 0.f) ? ta1 : SLOPE * ta1;
        float sA = fmaf(ta0, a2.x, ta1 * a2.y);
#pragma unroll
        for (int k = 1; k < 64; k <<= 1) sA += __shfl_xor(sA, k);
        float mn = fmaxf(m, sA);
        float sc = expf(m - mn);
        float pA = expf(sA - mn);
        den  = fmaf(den,  sc, pA);
        acc0 = fmaf(acc0, sc, pA * A.x);
        acc1 = fmaf(acc1, sc, pA * A.y);
    }
    float inv = 1.0f / (den + 1e-16f);
    *(float2*)(out + (size_t)node * HCD + c0) = make_float2(acc0 * inv, acc1 * inv);
}

// ---- BatchNorm statistics: per-channel sum and sum-of-squares ----
__global__ void bn_stats_kernel(const float* __restrict__ h, float* __restrict__ sum,
                                float* __restrict__ sumsq, int n) {
    int c = blockIdx.y * blockDim.x + threadIdx.x;   // 0..511
    int r0 = blockIdx.x * 128;
    int r1 = min(r0 + 128, n);
    float s = 0.f, s2 = 0.f;
    for (int r = r0; r < r1; ++r) {
        float v = h[(size_t)r * HCD + c];
        s += v;
        s2 = fmaf(v, v, s2);
    }
    atomicAdd(&sum[c], s);
    atomicAdd(&sumsq[c], s2);
}

__global__ void bn_finalize_kernel(const float* __restrict__ sum, const float* __restrict__ sumsq,
                                   const float* __restrict__ g, const float* __restrict__ b,
                                   float* __restrict__ scale, float* __restrict__ shift, int n) {
    int c = threadIdx.x;   // 512
    float inv_n = 1.0f / (float)n;
    float mu = sum[c] * inv_n;
    float var = fmaxf(sumsq[c] * inv_n - mu * mu, 0.0f);
    float sc = g[c] * rsqrtf(var + EPS_BN);
    scale[c] = sc;
    shift[c] = b[c] - mu * sc;
}

// ---- per-graph mean pool with fused BN+ReLU (batch is sorted) ----
__device__ __forceinline__ int lower_bound_i(const int* __restrict__ a, int n, int key) {
    int lo = 0, hi = n;
    while (lo < hi) {
        int mid = (lo + hi) >> 1;
        if (a[mid] < key) lo = mid + 1; else hi = mid;
    }
    return lo;
}

__global__ void pool_bnrelu_kernel(const float* __restrict__ h, const int* __restrict__ batch,
                                   const float* __restrict__ scale, const float* __restrict__ shift,
                                   float* __restrict__ pooled, int n) {
    int g = blockIdx.x;
    int c = threadIdx.x;   // 512
    int start = lower_bound_i(batch, n, g);
    int end   = lower_bound_i(batch, n, g + 1);
    float sc = scale[c], sh = shift[c];
    float s = 0.f;
    for (int r = start; r < end; ++r)
        s += fmaxf(fmaf(h[(size_t)r * HCD + c], sc, sh), 0.f);
    float cnt = (float)max(end - start, 1);
    pooled[(size_t)g * HCD + c] = s / cnt;
}

// ---- MLP head: relu([pooled|gfeat] @ fc1 + b1) @ fc2 + b2 ----
__global__ void head_kernel(const float* __restrict__ pooled, const float* __restrict__ gfeat,
                            const float* __restrict__ fc1w, const float* __restrict__ fc1b,
                            const float* __restrict__ fc2w, const float* __restrict__ fc2b,
                            float* __restrict__ out, int gdim) {
    int g = blockIdx.x;
    int j = threadIdx.x;   // 128
    float acc = fc1b[j];
    const float* prow = pooled + (size_t)g * HCD;
    for (int i = 0; i < HCD; ++i) acc = fmaf(prow[i], fc1w[i * CCH + j], acc);
    const float* grow = gfeat + (size_t)g * gdim;
    for (int i = 0; i < gdim; ++i) acc = fmaf(grow[i], fc1w[(HCD + i) * CCH + j], acc);
    acc = fmaxf(acc, 0.f);
    __shared__ float z[CCH];
    z[j] = acc * fc2w[j];
    __syncthreads();
    for (int s = CCH / 2; s > 0; s >>= 1) {
        if (j < s) z[j] += z[j + s];
        __syncthreads();
    }
    if (j == 0) out[g] = z[0] + fc2b[0];
}

extern "C" void kernel_launch(void* const* d_in, const int* in_sizes, int n_in,
                              void* d_out, int out_size, void* d_ws, size_t ws_size,
                              hipStream_t stream) {
    const float* x     = (const float*)d_in[0];
    const float* gfeat = (const float*)d_in[1];
    const float* W1l   = (const float*)d_in[2];
    const float* b1l   = (const float*)d_in[3];
    const float* W1r   = (const float*)d_in[4];
    const float* b1r   = (const float*)d_in[5];
    const float* att1  = (const float*)d_in[6];
    // d_in[7] = bias1: per-channel constant added right before BatchNorm -> cancels exactly
    const float* W2l   = (const float*)d_in[8];
    const float* b2l   = (const float*)d_in[9];
    const float* W2r   = (const float*)d_in[10];
    const float* b2r   = (const float*)d_in[11];
    const float* att2  = (const float*)d_in[12];
    // d_in[13] = bias2: cancels through BN
    const float* bn1_g = (const float*)d_in[14];
    const float* bn1_b = (const float*)d_in[15];
    const float* bn2_g = (const float*)d_in[16];
    const float* bn2_b = (const float*)d_in[17];
    const float* fc1w  = (const float*)d_in[18];
    const float* fc1b  = (const float*)d_in[19];
    const float* fc2w  = (const float*)d_in[20];
    const float* fc2b  = (const float*)d_in[21];
    const int* eidx    = (const int*)d_in[22];
    const int* batch   = (const int*)d_in[23];

    const int n    = in_sizes[0] / 9;
    const int E    = in_sizes[22] / 2;
    const int Etot = E + n;
    const int b    = out_size;
    const int gdim = in_sizes[1] / b;
    const int* esrc = eidx;
    const int* edst = eidx + E;

    float* ws = (float*)d_ws;
    size_t nHC = (size_t)n * HCD;
    float* xl      = ws;
    float* xr      = xl + nHC;
    float* hbuf    = xr + nHC;
    int* deg       = (int*)(hbuf + nHC);     // n
    int* rowstart  = deg + n;                // n+1
    int* cursor    = rowstart + n + 1;       // n
    int* s_src     = cursor + n;             // Etot
    float* bnsum   = (float*)(s_src + Etot); // 512
    float* bnsumsq = bnsum + HCD;            // 512
    float* bnscale = bnsumsq + HCD;          // 512
    float* bnshift = bnscale + HCD;          // 512
    float* pooled  = bnshift + HCD;          // b*512

    const int BLK = 256;
    const int linBlocks  = (int)((nHC + BLK - 1) / BLK);
    const int eBlocks    = (Etot + BLK - 1) / BLK;
    const int bnxBlocks  = (n + 127) / 128;
    dim3 gemmGrid((n + 127) / 128, 8);

    // ---------------- CSR build (shared by both layers) ----------------
    hipMemsetAsync(deg, 0, (size_t)(2 * n + 1) * sizeof(int), stream);  // deg + rowstart head
    hipMemsetAsync(cursor, 0, (size_t)n * sizeof(int), stream);
    hist_kernel<<<eBlocks, BLK, 0, stream>>>(edst, deg, E, Etot);
    scan_kernel<<<1, 1024, 0, stream>>>(deg, rowstart, n);
    scatter_kernel<<<eBlocks, BLK, 0, stream>>>(esrc, edst, rowstart, cursor, s_src, E, Etot);

    // ---------------- layer 1 ----------------
    lin1_kernel<<<linBlocks, BLK, 0, stream>>>(x, W1l, b1l, W1r, b1r, xl, xr, n);
    gat_fused_kernel<<<n, 256, 0, stream>>>(xl, xr, att1, rowstart, s_src, hbuf);
    hipMemsetAsync(bnsum, 0, HCD * 2 * sizeof(float), stream);
    bn_stats_kernel<<<dim3(bnxBlocks, 2), BLK, 0, stream>>>(hbuf, bnsum, bnsumsq, n);
    bn_finalize_kernel<<<1, HCD, 0, stream>>>(bnsum, bnsumsq, bn1_g, bn1_b, bnscale, bnshift, n);

    // ---------------- layer 2 (BN1+ReLU fused into GEMM A-staging) ----------------
    gemm_dual_kernel<<<gemmGrid, BLK, 0, stream>>>(hbuf, W2l, b2l, W2r, b2r,
                                                   bnscale, bnshift, xl, xr, n);
    gat_fused_kernel<<<n, 256, 0, stream>>>(xl, xr, att2, rowstart, s_src, hbuf);
    hipMemsetAsync(bnsum, 0, HCD * 2 * sizeof(float), stream);
    bn_stats_kernel<<<dim3(bnxBlocks, 2), BLK, 0, stream>>>(hbuf, bnsum, bnsumsq, n);
    bn_finalize_kernel<<<1, HCD, 0, stream>>>(bnsum, bnsumsq, bn2_g, bn2_b, bnscale, bnshift, n);

    // ---------------- readout (BN2+ReLU fused into pool) ----------------
    pool_bnrelu_kernel<<<b, HCD, 0, stream>>>(hbuf, batch, bnscale, bnshift, pooled, n);
    head_kernel<<<b, CCH, 0, stream>>>(pooled, gfeat, fc1w, fc1b, fc2w, fc2b, (float*)d_out, gdim);
}

// Round 9
// 907.235 us; speedup vs baseline: 5.3669x; 1.2036x over previous
//
#include <hip/hip_runtime.h>
#include <math.h>

#define NHEAD 4
#define CCH 128
#define HCD 512
#define SLOPE 0.2f
#define EPS_BN 1e-5f

typedef short s8v __attribute__((ext_vector_type(8)));
typedef float f32x4 __attribute__((ext_vector_type(4)));

// RNE f32 -> bf16 (finite values), and back
__device__ __forceinline__ unsigned short f2bf(float f) {
    unsigned int u = __float_as_uint(f);
    return (unsigned short)((u + 0x7FFFu + ((u >> 16) & 1u)) >> 16);
}
__device__ __forceinline__ float bf2f(unsigned short b) {
    return __uint_as_float(((unsigned int)b) << 16);
}

// ---- layer 1 node transforms: x[N,9] @ W[9,512] + b, both l and r ----
__global__ void lin1_kernel(const float* __restrict__ x,
                            const float* __restrict__ Wl, const float* __restrict__ bl,
                            const float* __restrict__ Wr, const float* __restrict__ br,
                            float* __restrict__ xl, float* __restrict__ xr, int n) {
    int gid = blockIdx.x * blockDim.x + threadIdx.x;
    if (gid >= n * HCD) return;
    int node = gid >> 9;
    int c = gid & (HCD - 1);
    const float* xrow = x + node * 9;
    float a = bl[c], bz = br[c];
#pragma unroll
    for (int k = 0; k < 9; ++k) {
        float xv = xrow[k];
        a  = fmaf(xv, Wl[k * HCD + c], a);
        bz = fmaf(xv, Wr[k * HCD + c], bz);
    }
    xl[gid] = a;
    xr[gid] = bz;
}

// ---- split A = relu(bn(h)) into bf16 hi/lo, row-major [n][512] ----
__global__ void splitA_kernel(const float* __restrict__ h,
                              const float* __restrict__ scale, const float* __restrict__ shift,
                              unsigned short* __restrict__ Ah, unsigned short* __restrict__ Al,
                              int total4) {
    int gid = blockIdx.x * blockDim.x + threadIdx.x;
    if (gid >= total4) return;
    int c4 = gid & 127;
    float4 v = ((const float4*)h)[gid];
    float4 sc = ((const float4*)scale)[c4];
    float4 sh = ((const float4*)shift)[c4];
    float f0 = fmaxf(fmaf(v.x, sc.x, sh.x), 0.f);
    float f1 = fmaxf(fmaf(v.y, sc.y, sh.y), 0.f);
    float f2 = fmaxf(fmaf(v.z, sc.z, sh.z), 0.f);
    float f3 = fmaxf(fmaf(v.w, sc.w, sh.w), 0.f);
    unsigned short h0 = f2bf(f0), h1 = f2bf(f1), h2 = f2bf(f2), h3 = f2bf(f3);
    short4 hv = make_short4((short)h0, (short)h1, (short)h2, (short)h3);
    short4 lv = make_short4((short)f2bf(f0 - bf2f(h0)), (short)f2bf(f1 - bf2f(h1)),
                            (short)f2bf(f2 - bf2f(h2)), (short)f2bf(f3 - bf2f(h3)));
    ((short4*)Ah)[gid] = hv;
    ((short4*)Al)[gid] = lv;
}

// ---- split + transpose W[k][col] -> BT[col][k] bf16 hi/lo, both matrices ----
__global__ void splitBT_kernel(const float* __restrict__ Wl, const float* __restrict__ Wr,
                               unsigned short* __restrict__ BThl, unsigned short* __restrict__ BTll,
                               unsigned short* __restrict__ BThr, unsigned short* __restrict__ BTlr) {
    int gid = blockIdx.x * blockDim.x + threadIdx.x;   // 512*512
    int col = gid >> 9;
    int k = gid & 511;
    float vl = Wl[k * HCD + col];
    float vr = Wr[k * HCD + col];
    unsigned short hl = f2bf(vl);
    unsigned short hr = f2bf(vr);
    BThl[gid] = hl; BTll[gid] = f2bf(vl - bf2f(hl));
    BThr[gid] = hr; BTlr[gid] = f2bf(vr - bf2f(hr));
}

// ---- split-bf16 MFMA GEMM: C = A @ B + bias for both weight matrices ----
// grid.y<4 -> outL cols y*128 ; y>=4 -> outR. 128x128 tile, 4 waves (64x64 each).
// LDS staged in fragment order so every ds_read_b128 is at lane*16 (conflict-free).
__global__ __launch_bounds__(256) void gemm_mfma_kernel(
        const unsigned short* __restrict__ Ah, const unsigned short* __restrict__ Al,
        const unsigned short* __restrict__ BThL, const unsigned short* __restrict__ BTlL,
        const unsigned short* __restrict__ BThR, const unsigned short* __restrict__ BTlR,
        const float* __restrict__ biasl, const float* __restrict__ biasr,
        float* __restrict__ outL, float* __restrict__ outR, int M) {
    __shared__ short sAh[4096], sAl[4096], sBh[4096], sBl[4096];  // 4x 128x32 bf16 = 32 KB
    const int y = blockIdx.y;
    const unsigned short* BTh = (y < 4) ? BThL : BThR;
    const unsigned short* BTl = (y < 4) ? BTlL : BTlR;
    const float* bias = (y < 4) ? biasl : biasr;
    float* C = (y < 4) ? outL : outR;
    const int col0 = (y & 3) * 128;
    const int row0 = blockIdx.x * 128;
    const int tid  = threadIdx.x;
    const int wave = tid >> 6;
    const int lane = tid & 63;

    f32x4 acc[4][4];
#pragma unroll
    for (int i = 0; i < 4; ++i)
#pragma unroll
        for (int j = 0; j < 4; ++j) acc[i][j] = (f32x4){0.f, 0.f, 0.f, 0.f};

    const int abase = (wave & 1) * 2048;   // short offset of wave's 64-row half
    const int bbase = (wave >> 1) * 2048;  // short offset of wave's 64-col half

    for (int k0 = 0; k0 < 512; k0 += 32) {
        __syncthreads();
#pragma unroll
        for (int cc = 0; cc < 2; ++cc) {
            int ch = tid + cc * 256;        // 0..511
            int r  = ch >> 2;               // tile row / col 0..127
            int kb = ch & 3;                // 16B chunk within 32-k
            int lds = (r >> 4) * 512 + ((kb * 16 + (r & 15)) * 8);  // frag-order (shorts)
            s8v va, vb;
            if (row0 + r < M) {
                va = *(const s8v*)(Ah + (size_t)(row0 + r) * 512 + k0 + kb * 8);
                vb = *(const s8v*)(Al + (size_t)(row0 + r) * 512 + k0 + kb * 8);
            } else {
                va = (s8v){0,0,0,0,0,0,0,0};
                vb = (s8v){0,0,0,0,0,0,0,0};
            }
            *(s8v*)&sAh[lds] = va;
            *(s8v*)&sAl[lds] = vb;
            s8v wh = *(const s8v*)(BTh + (size_t)(col0 + r) * 512 + k0 + kb * 8);
            s8v wl = *(const s8v*)(BTl + (size_t)(col0 + r) * 512 + k0 + kb * 8);
            *(s8v*)&sBh[lds] = wh;
            *(s8v*)&sBl[lds] = wl;
        }
        __syncthreads();
#pragma unroll
        for (int sr = 0; sr < 4; ++sr) {
            s8v ah = *(const s8v*)&sAh[abase + sr * 512 + lane * 8];
            s8v al = *(const s8v*)&sAl[abase + sr * 512 + lane * 8];
#pragma unroll
            for (int sc = 0; sc < 4; ++sc) {
                s8v bh = *(const s8v*)&sBh[bbase + sc * 512 + lane * 8];
                s8v bl = *(const s8v*)&sBl[bbase + sc * 512 + lane * 8];
                acc[sr][sc] = __builtin_amdgcn_mfma_f32_16x16x32_bf16(ah, bh, acc[sr][sc], 0, 0, 0);
                acc[sr][sc] = __builtin_amdgcn_mfma_f32_16x16x32_bf16(al, bh, acc[sr][sc], 0, 0, 0);
                acc[sr][sc] = __builtin_amdgcn_mfma_f32_16x16x32_bf16(ah, bl, acc[sr][sc], 0, 0, 0);
            }
        }
    }
    // C/D frag layout (m89): col = lane&15, row = (lane>>4)*4 + j
    const int crow = row0 + (wave & 1) * 64;
    const int ccol = col0 + (wave >> 1) * 64;
#pragma unroll
    for (int sr = 0; sr < 4; ++sr) {
        int rbase = crow + sr * 16 + ((lane >> 4) << 2);
#pragma unroll
        for (int sc = 0; sc < 4; ++sc) {
            int col = ccol + sc * 16 + (lane & 15);
            float bb = bias[col];
#pragma unroll
            for (int j = 0; j < 4; ++j) {
                int r = rbase + j;
                if (r < M) C[(size_t)r * 512 + col] = acc[sr][sc][j] + bb;
            }
        }
    }
}

// ================= CSR build (once per launch; graph shared by both layers) =================

__global__ void hist_kernel(const int* __restrict__ edst, int* __restrict__ deg, int E, int Etot) {
    int e = blockIdx.x * blockDim.x + threadIdx.x;
    if (e >= Etot) return;
    int dst = (e < E) ? edst[e] : (e - E);
    atomicAdd(&deg[dst], 1);
}

__global__ __launch_bounds__(1024) void scan_kernel(const int* __restrict__ deg,
                                                    int* __restrict__ rowstart, int n) {
    __shared__ int buf[1024];
    __shared__ int carry;
    if (threadIdx.x == 0) carry = 0;
    __syncthreads();
    for (int base = 0; base < n; base += 1024) {
        int i = base + (int)threadIdx.x;
        int v = (i < n) ? deg[i] : 0;
        buf[threadIdx.x] = v;
        __syncthreads();
        for (int off = 1; off < 1024; off <<= 1) {
            int t = (threadIdx.x >= (unsigned)off) ? buf[threadIdx.x - off] : 0;
            __syncthreads();
            buf[threadIdx.x] += t;
            __syncthreads();
        }
        if (i < n) rowstart[i] = carry + buf[threadIdx.x] - v;
        int blocksum = buf[1023];
        __syncthreads();
        if (threadIdx.x == 0) carry += blocksum;
        __syncthreads();
    }
    if (threadIdx.x == 0) rowstart[n] = carry;
}

__global__ void scatter_kernel(const int* __restrict__ esrc, const int* __restrict__ edst,
                               const int* __restrict__ rowstart, int* __restrict__ cursor,
                               int* __restrict__ s_src, int E, int Etot) {
    int e = blockIdx.x * blockDim.x + threadIdx.x;
    if (e >= Etot) return;
    int src = (e < E) ? esrc[e] : (e - E);
    int dst = (e < E) ? edst[e] : (e - E);
    int pos = rowstart[dst] + atomicAdd(&cursor[dst], 1);
    s_src[pos] = src;
}

// ---- fully fused GATv2 edge phase (2-edge-unrolled online softmax) ----
__global__ __launch_bounds__(256) void gat_fused_kernel(
        const float* __restrict__ xl, const float* __restrict__ xr,
        const float* __restrict__ att,
        const int* __restrict__ rowstart, const int* __restrict__ s_src,
        float* __restrict__ out) {
    int node = blockIdx.x;
    int h    = threadIdx.x >> 6;
    int lane = threadIdx.x & 63;
    int beg = rowstart[node];
    int end = rowstart[node + 1];
    int c0 = h * CCH + (lane << 1);
    float2 r2 = *(const float2*)(xr + (size_t)node * HCD + c0);
    float2 a2 = *(const float2*)(att + c0);
    float m = -3.0e38f, den = 0.f, acc0 = 0.f, acc1 = 0.f;

    int j = beg;
    float2 lA = *(const float2*)(xl + (size_t)s_src[j] * HCD + c0);   // deg >= 1 (self-loop)
    float2 lB;
    if (j + 1 < end) lB = *(const float2*)(xl + (size_t)s_src[j + 1] * HCD + c0);

    while (j + 1 < end) {
        float2 A = lA, B = lB;
        if (j + 2 < end) lA = *(const float2*)(xl + (size_t)s_src[j + 2] * HCD + c0);
        if (j + 3 < end) lB = *(const float2*)(xl + (size_t)s_src[j + 3] * HCD + c0);
        float ta0 = A.x + r2.x; ta0 = (ta0 > 0.f) ? ta0 : SLOPE * ta0;
        float ta1 = A.y + r2.y; ta1 = (ta1 > 0.f) ? ta1 : SLOPE * ta1;
        float tb0 = B.x + r2.x; tb0 = (tb0 > 0.f) ? tb0 : SLOPE * tb0;
        float tb1 = B.y + r2.y; tb1 = (tb1 > 0.f) ? tb1 : SLOPE * tb1;
        float sA = fmaf(ta0, a2.x, ta1 * a2.y);
        float sB = fmaf(tb0, a2.x, tb1 * a2.y);
#pragma unroll
        for (int k = 1; k < 64; k <<= 1) {
            sA += __shfl_xor(sA, k);
            sB += __shfl_xor(sB, k);
        }
        float mn = fmaxf(m, fmaxf(sA, sB));
        float sc = expf(m - mn);
        float pA = expf(sA - mn);
        float pB = expf(sB - mn);
        den  = fmaf(den,  sc, pA + pB);
        acc0 = fmaf(acc0, sc, fmaf(pA, A.x, pB * B.x));
        acc1 = fmaf(acc1, sc, fmaf(pA, A.y, pB * B.y));
        m = mn;
        j += 2;
    }
    if (j < end) {   // odd tail
        float2 A = lA;
        float ta0 = A.x + r2.x; ta0 = (ta0 > 0.f) ? ta0 : SLOPE * ta0;
        float ta1 = A.y + r2.y; ta1 = (ta1 > 0.f) ? ta1 : SLOPE * ta1;
        float sA = fmaf(ta0, a2.x, ta1 * a2.y);
#pragma unroll
        for (int k = 1; k < 64; k <<= 1) sA += __shfl_xor(sA, k);
        float mn = fmaxf(m, sA);
        float sc = expf(m - mn);
        float pA = expf(sA - mn);
        den  = fmaf(den,  sc, pA);
        acc0 = fmaf(acc0, sc, pA * A.x);
        acc1 = fmaf(acc1, sc, pA * A.y);
    }
    float inv = 1.0f / (den + 1e-16f);
    *(float2*)(out + (size_t)node * HCD + c0) = make_float2(acc0 * inv, acc1 * inv);
}

// ---- BatchNorm statistics: per-channel sum and sum-of-squares ----
__global__ void bn_stats_kernel(const float* __restrict__ h, float* __restrict__ sum,
                                float* __restrict__ sumsq, int n) {
    int c = blockIdx.y * blockDim.x + threadIdx.x;   // 0..511
    int r0 = blockIdx.x * 128;
    int r1 = min(r0 + 128, n);
    float s = 0.f, s2 = 0.f;
    for (int r = r0; r < r1; ++r) {
        float v = h[(size_t)r * HCD + c];
        s += v;
        s2 = fmaf(v, v, s2);
    }
    atomicAdd(&sum[c], s);
    atomicAdd(&sumsq[c], s2);
}

__global__ void bn_finalize_kernel(const float* __restrict__ sum, const float* __restrict__ sumsq,
                                   const float* __restrict__ g, const float* __restrict__ b,
                                   float* __restrict__ scale, float* __restrict__ shift, int n) {
    int c = threadIdx.x;   // 512
    float inv_n = 1.0f / (float)n;
    float mu = sum[c] * inv_n;
    float var = fmaxf(sumsq[c] * inv_n - mu * mu, 0.0f);
    float sc = g[c] * rsqrtf(var + EPS_BN);
    scale[c] = sc;
    shift[c] = b[c] - mu * sc;
}

// ---- per-graph mean pool with fused BN+ReLU (batch is sorted) ----
__device__ __forceinline__ int lower_bound_i(const int* __restrict__ a, int n, int key) {
    int lo = 0, hi = n;
    while (lo < hi) {
        int mid = (lo + hi) >> 1;
        if (a[mid] < key) lo = mid + 1; else hi = mid;
    }
    return lo;
}

__global__ void pool_bnrelu_kernel(const float* __restrict__ h, const int* __restrict__ batch,
                                   const float* __restrict__ scale, const float* __restrict__ shift,
                                   float* __restrict__ pooled, int n) {
    int g = blockIdx.x;
    int c = threadIdx.x;   // 512
    int start = lower_bound_i(batch, n, g);
    int end   = lower_bound_i(batch, n, g + 1);
    float sc = scale[c], sh = shift[c];
    float s = 0.f;
    for (int r = start; r < end; ++r)
        s += fmaxf(fmaf(h[(size_t)r * HCD + c], sc, sh), 0.f);
    float cnt = (float)max(end - start, 1);
    pooled[(size_t)g * HCD + c] = s / cnt;
}

// ---- MLP head: relu([pooled|gfeat] @ fc1 + b1) @ fc2 + b2 ----
__global__ void head_kernel(const float* __restrict__ pooled, const float* __restrict__ gfeat,
                            const float* __restrict__ fc1w, const float* __restrict__ fc1b,
                            const float* __restrict__ fc2w, const float* __restrict__ fc2b,
                            float* __restrict__ out, int gdim) {
    int g = blockIdx.x;
    int j = threadIdx.x;   // 128
    float acc = fc1b[j];
    const float* prow = pooled + (size_t)g * HCD;
    for (int i = 0; i < HCD; ++i) acc = fmaf(prow[i], fc1w[i * CCH + j], acc);
    const float* grow = gfeat + (size_t)g * gdim;
    for (int i = 0; i < gdim; ++i) acc = fmaf(grow[i], fc1w[(HCD + i) * CCH + j], acc);
    acc = fmaxf(acc, 0.f);
    __shared__ float z[CCH];
    z[j] = acc * fc2w[j];
    __syncthreads();
    for (int s = CCH / 2; s > 0; s >>= 1) {
        if (j < s) z[j] += z[j + s];
        __syncthreads();
    }
    if (j == 0) out[g] = z[0] + fc2b[0];
}

extern "C" void kernel_launch(void* const* d_in, const int* in_sizes, int n_in,
                              void* d_out, int out_size, void* d_ws, size_t ws_size,
                              hipStream_t stream) {
    const float* x     = (const float*)d_in[0];
    const float* gfeat = (const float*)d_in[1];
    const float* W1l   = (const float*)d_in[2];
    const float* b1l   = (const float*)d_in[3];
    const float* W1r   = (const float*)d_in[4];
    const float* b1r   = (const float*)d_in[5];
    const float* att1  = (const float*)d_in[6];
    // d_in[7] = bias1: cancels through BN
    const float* W2l   = (const float*)d_in[8];
    const float* b2l   = (const float*)d_in[9];
    const float* W2r   = (const float*)d_in[10];
    const float* b2r   = (const float*)d_in[11];
    const float* att2  = (const float*)d_in[12];
    // d_in[13] = bias2: cancels through BN
    const float* bn1_g = (const float*)d_in[14];
    const float* bn1_b = (const float*)d_in[15];
    const float* bn2_g = (const float*)d_in[16];
    const float* bn2_b = (const float*)d_in[17];
    const float* fc1w  = (const float*)d_in[18];
    const float* fc1b  = (const float*)d_in[19];
    const float* fc2w  = (const float*)d_in[20];
    const float* fc2b  = (const float*)d_in[21];
    const int* eidx    = (const int*)d_in[22];
    const int* batch   = (const int*)d_in[23];

    const int n    = in_sizes[0] / 9;
    const int E    = in_sizes[22] / 2;
    const int Etot = E + n;
    const int b    = out_size;
    const int gdim = in_sizes[1] / b;
    const int* esrc = eidx;
    const int* edst = eidx + E;

    float* ws = (float*)d_ws;
    size_t nHC = (size_t)n * HCD;
    float* xl      = ws;
    float* xr      = xl + nHC;
    float* hbuf    = xr + nHC;
    int* deg       = (int*)(hbuf + nHC);     // n
    int* rowstart  = deg + n;                // n+1
    int* cursor    = rowstart + n + 1;       // n
    int* s_src     = cursor + n;             // Etot
    float* bnsum   = (float*)(s_src + Etot); // 512
    float* bnsumsq = bnsum + HCD;            // 512
    float* bnscale = bnsumsq + HCD;          // 512
    float* bnshift = bnscale + HCD;          // 512
    float* pooled  = bnshift + HCD;          // b*512
    unsigned short* Ah   = (unsigned short*)(pooled + (size_t)b * HCD);  // n*512 bf16
    unsigned short* Al   = Ah + nHC;
    unsigned short* BThl = Al + nHC;         // 512*512 each
    unsigned short* BTll = BThl + HCD * HCD;
    unsigned short* BThr = BTll + HCD * HCD;
    unsigned short* BTlr = BThr + HCD * HCD;

    const int BLK = 256;
    const int linBlocks  = (int)((nHC + BLK - 1) / BLK);
    const int eBlocks    = (Etot + BLK - 1) / BLK;
    const int bnxBlocks  = (n + 127) / 128;
    const int saBlocks   = (int)((nHC / 4 + BLK - 1) / BLK);
    dim3 gemmGrid((n + 127) / 128, 8);

    // ---------------- CSR build (shared by both layers) ----------------
    hipMemsetAsync(deg, 0, (size_t)(2 * n + 1) * sizeof(int), stream);
    hipMemsetAsync(cursor, 0, (size_t)n * sizeof(int), stream);
    hist_kernel<<<eBlocks, BLK, 0, stream>>>(edst, deg, E, Etot);
    scan_kernel<<<1, 1024, 0, stream>>>(deg, rowstart, n);
    scatter_kernel<<<eBlocks, BLK, 0, stream>>>(esrc, edst, rowstart, cursor, s_src, E, Etot);
    // weight split/transpose (graph-independent)
    splitBT_kernel<<<(HCD * HCD) / BLK, BLK, 0, stream>>>(W2l, W2r, BThl, BTll, BThr, BTlr);

    // ---------------- layer 1 ----------------
    lin1_kernel<<<linBlocks, BLK, 0, stream>>>(x, W1l, b1l, W1r, b1r, xl, xr, n);
    gat_fused_kernel<<<n, 256, 0, stream>>>(xl, xr, att1, rowstart, s_src, hbuf);
    hipMemsetAsync(bnsum, 0, HCD * 2 * sizeof(float), stream);
    bn_stats_kernel<<<dim3(bnxBlocks, 2), BLK, 0, stream>>>(hbuf, bnsum, bnsumsq, n);
    bn_finalize_kernel<<<1, HCD, 0, stream>>>(bnsum, bnsumsq, bn1_g, bn1_b, bnscale, bnshift, n);

    // ---------------- layer 2: BN1+ReLU fused into split; MFMA GEMM ----------------
    splitA_kernel<<<saBlocks, BLK, 0, stream>>>(hbuf, bnscale, bnshift, Ah, Al, (int)(nHC / 4));
    gemm_mfma_kernel<<<gemmGrid, BLK, 0, stream>>>(Ah, Al, BThl, BTll, BThr, BTlr,
                                                   b2l, b2r, xl, xr, n);
    gat_fused_kernel<<<n, 256, 0, stream>>>(xl, xr, att2, rowstart, s_src, hbuf);
    hipMemsetAsync(bnsum, 0, HCD * 2 * sizeof(float), stream);
    bn_stats_kernel<<<dim3(bnxBlocks, 2), BLK, 0, stream>>>(hbuf, bnsum, bnsumsq, n);
    bn_finalize_kernel<<<1, HCD, 0, stream>>>(bnsum, bnsumsq, bn2_g, bn2_b, bnscale, bnshift, n);

    // ---------------- readout (BN2+ReLU fused into pool) ----------------
    pool_bnrelu_kernel<<<b, HCD, 0, stream>>>(hbuf, batch, bnscale, bnshift, pooled, n);
    head_kernel<<<b, CCH, 0, stream>>>(pooled, gfeat, fc1w, fc1b, fc2w, fc2b, (float*)d_out, gdim);
}

// Round 12
// 861.725 us; speedup vs baseline: 5.6504x; 1.0528x over previous
//
#include <hip/hip_runtime.h>
#include <math.h>

#define NHEAD 4
#define CCH 128
#define HCD 512
#define SLOPE 0.2f
#define EPS_BN 1e-5f

typedef short s8v __attribute__((ext_vector_type(8)));
typedef float f32x4 __attribute__((ext_vector_type(4)));

// RNE f32 -> bf16 (finite values), and back
__device__ __forceinline__ unsigned short f2bf(float f) {
    unsigned int u = __float_as_uint(f);
    return (unsigned short)((u + 0x7FFFu + ((u >> 16) & 1u)) >> 16);
}
__device__ __forceinline__ float bf2f(unsigned short b) {
    return __uint_as_float(((unsigned int)b) << 16);
}

// ---- layer 1 node transforms: x[N,9] @ W[9,512] + b, both l and r ----
__global__ void lin1_kernel(const float* __restrict__ x,
                            const float* __restrict__ Wl, const float* __restrict__ bl,
                            const float* __restrict__ Wr, const float* __restrict__ br,
                            float* __restrict__ xl, float* __restrict__ xr, int n) {
    int gid = blockIdx.x * blockDim.x + threadIdx.x;
    if (gid >= n * HCD) return;
    int node = gid >> 9;
    int c = gid & (HCD - 1);
    const float* xrow = x + node * 9;
    float a = bl[c], bz = br[c];
#pragma unroll
    for (int k = 0; k < 9; ++k) {
        float xv = xrow[k];
        a  = fmaf(xv, Wl[k * HCD + c], a);
        bz = fmaf(xv, Wr[k * HCD + c], bz);
    }
    xl[gid] = a;
    xr[gid] = bz;
}

// ---- split A = relu(bn(h)) into bf16 hi/lo, row-major [n][512] ----
__global__ void splitA_kernel(const float* __restrict__ h,
                              const float* __restrict__ scale, const float* __restrict__ shift,
                              unsigned short* __restrict__ Ah, unsigned short* __restrict__ Al,
                              int total4) {
    int gid = blockIdx.x * blockDim.x + threadIdx.x;
    if (gid >= total4) return;
    int c4 = gid & 127;
    float4 v = ((const float4*)h)[gid];
    float4 sc = ((const float4*)scale)[c4];
    float4 sh = ((const float4*)shift)[c4];
    float f0 = fmaxf(fmaf(v.x, sc.x, sh.x), 0.f);
    float f1 = fmaxf(fmaf(v.y, sc.y, sh.y), 0.f);
    float f2 = fmaxf(fmaf(v.z, sc.z, sh.z), 0.f);
    float f3 = fmaxf(fmaf(v.w, sc.w, sh.w), 0.f);
    unsigned short h0 = f2bf(f0), h1 = f2bf(f1), h2 = f2bf(f2), h3 = f2bf(f3);
    short4 hv = make_short4((short)h0, (short)h1, (short)h2, (short)h3);
    short4 lv = make_short4((short)f2bf(f0 - bf2f(h0)), (short)f2bf(f1 - bf2f(h1)),
                            (short)f2bf(f2 - bf2f(h2)), (short)f2bf(f3 - bf2f(h3)));
    ((short4*)Ah)[gid] = hv;
    ((short4*)Al)[gid] = lv;
}

// ---- split + transpose W[k][col] -> BT[col][k] bf16 hi/lo, both matrices ----
__global__ void splitBT_kernel(const float* __restrict__ Wl, const float* __restrict__ Wr,
                               unsigned short* __restrict__ BThl, unsigned short* __restrict__ BTll,
                               unsigned short* __restrict__ BThr, unsigned short* __restrict__ BTlr) {
    int gid = blockIdx.x * blockDim.x + threadIdx.x;   // 512*512
    int col = gid >> 9;
    int k = gid & 511;
    float vl = Wl[k * HCD + col];
    float vr = Wr[k * HCD + col];
    unsigned short hl = f2bf(vl);
    unsigned short hr = f2bf(vr);
    BThl[gid] = hl; BTll[gid] = f2bf(vl - bf2f(hl));
    BThr[gid] = hr; BTlr[gid] = f2bf(vr - bf2f(hr));
}

// ---- split-bf16 MFMA GEMM, reg-prefetch pipelined, XCD-swizzled ----
// 1D grid nrt*8 blocks; logical = (b&7)*nrt + b>>3 (bijective, rowtile-major
// chunks per XCD); rowtile = l>>3; y = l&7 (y<4 -> L matrix, else R).
// LDS fragment-order with row^=(kb<<1) XOR on store AND read (phase-spread).
__global__ __launch_bounds__(256) void gemm_mfma_kernel(
        const unsigned short* __restrict__ Ah, const unsigned short* __restrict__ Al,
        const unsigned short* __restrict__ BThL, const unsigned short* __restrict__ BTlL,
        const unsigned short* __restrict__ BThR, const unsigned short* __restrict__ BTlR,
        const float* __restrict__ biasl, const float* __restrict__ biasr,
        float* __restrict__ outL, float* __restrict__ outR, int M) {
    __shared__ short sAh[4096], sAl[4096], sBh[4096], sBl[4096];  // 32 KB
    const int nrt = gridDim.x >> 3;
    const int bphys = blockIdx.x;
    const int l = (bphys & 7) * nrt + (bphys >> 3);
    const int y = l & 7;
    const int row0 = (l >> 3) * 128;
    const unsigned short* BTh = (y < 4) ? BThL : BThR;
    const unsigned short* BTl = (y < 4) ? BTlL : BTlR;
    const float* bias = (y < 4) ? biasl : biasr;
    float* C = (y < 4) ? outL : outR;
    const int col0 = (y & 3) * 128;
    const int tid  = threadIdx.x;
    const int wave = tid >> 6;
    const int lane = tid & 63;
    const int str = tid >> 2;            // staging row (cc=0 half)
    const int skb = tid & 3;             // staging 16B chunk

    f32x4 acc[4][4];
#pragma unroll
    for (int i = 0; i < 4; ++i)
#pragma unroll
        for (int j = 0; j < 4; ++j) acc[i][j] = (f32x4){0.f, 0.f, 0.f, 0.f};

    const int abase = (wave & 1) * 2048;
    const int bbase = (wave >> 1) * 2048;
    // read idx: lane -> (kb=lane>>4, row=lane&15), row XOR (kb<<1)
    const int rkb = lane >> 4;
    const int rrow = (lane & 15) ^ (rkb << 1);
    const int roff = rkb * 128 + rrow * 8;

    s8v pAh[2], pAl[2], pBh[2], pBl[2];
    const s8v zero8 = (s8v){0,0,0,0,0,0,0,0};

#define GLOAD(k0)                                                                     \
    {                                                                                 \
        _Pragma("unroll")                                                             \
        for (int cc = 0; cc < 2; ++cc) {                                              \
            int r = str + cc * 64;                                                    \
            if (row0 + r < M) {                                                       \
                pAh[cc] = *(const s8v*)(Ah + (size_t)(row0 + r) * 512 + (k0) + skb * 8); \
                pAl[cc] = *(const s8v*)(Al + (size_t)(row0 + r) * 512 + (k0) + skb * 8); \
            } else { pAh[cc] = zero8; pAl[cc] = zero8; }                              \
            pBh[cc] = *(const s8v*)(BTh + (size_t)(col0 + r) * 512 + (k0) + skb * 8); \
            pBl[cc] = *(const s8v*)(BTl + (size_t)(col0 + r) * 512 + (k0) + skb * 8); \
        }                                                                             \
    }

    GLOAD(0);
    for (int k0 = 0; k0 < 512; k0 += 32) {
        __syncthreads();
#pragma unroll
        for (int cc = 0; cc < 2; ++cc) {
            int r = str + cc * 64;
            int idx = (r >> 4) * 512 + skb * 128 + (((r & 15) ^ (skb << 1)) * 8);
            *(s8v*)&sAh[idx] = pAh[cc];
            *(s8v*)&sAl[idx] = pAl[cc];
            *(s8v*)&sBh[idx] = pBh[cc];
            *(s8v*)&sBl[idx] = pBl[cc];
        }
        __syncthreads();
        if (k0 + 32 < 512) GLOAD(k0 + 32);   // in flight across the MFMA block
#pragma unroll
        for (int sr = 0; sr < 4; ++sr) {
            s8v ah = *(const s8v*)&sAh[abase + sr * 512 + roff];
            s8v al = *(const s8v*)&sAl[abase + sr * 512 + roff];
#pragma unroll
            for (int sc = 0; sc < 4; ++sc) {
                s8v bh = *(const s8v*)&sBh[bbase + sc * 512 + roff];
                s8v bl = *(const s8v*)&sBl[bbase + sc * 512 + roff];
                acc[sr][sc] = __builtin_amdgcn_mfma_f32_16x16x32_bf16(ah, bh, acc[sr][sc], 0, 0, 0);
                acc[sr][sc] = __builtin_amdgcn_mfma_f32_16x16x32_bf16(al, bh, acc[sr][sc], 0, 0, 0);
                acc[sr][sc] = __builtin_amdgcn_mfma_f32_16x16x32_bf16(ah, bl, acc[sr][sc], 0, 0, 0);
            }
        }
    }
#undef GLOAD
    // C/D frag layout (m89): col = lane&15, row = (lane>>4)*4 + j
    const int crow = row0 + (wave & 1) * 64;
    const int ccol = col0 + (wave >> 1) * 64;
#pragma unroll
    for (int sr = 0; sr < 4; ++sr) {
        int rbase = crow + sr * 16 + ((lane >> 4) << 2);
#pragma unroll
        for (int sc = 0; sc < 4; ++sc) {
            int col = ccol + sc * 16 + (lane & 15);
            float bb = bias[col];
#pragma unroll
            for (int j = 0; j < 4; ++j) {
                int r = rbase + j;
                if (r < M) C[(size_t)r * 512 + col] = acc[sr][sc][j] + bb;
            }
        }
    }
}

// ================= CSR build (once per launch; graph shared by both layers) =================

__global__ void hist_kernel(const int* __restrict__ edst, int* __restrict__ deg, int E, int Etot) {
    int e = blockIdx.x * blockDim.x + threadIdx.x;
    if (e >= Etot) return;
    int dst = (e < E) ? edst[e] : (e - E);
    atomicAdd(&deg[dst], 1);
}

__global__ __launch_bounds__(1024) void scan_kernel(const int* __restrict__ deg,
                                                    int* __restrict__ rowstart, int n) {
    __shared__ int buf[1024];
    __shared__ int carry;
    if (threadIdx.x == 0) carry = 0;
    __syncthreads();
    for (int base = 0; base < n; base += 1024) {
        int i = base + (int)threadIdx.x;
        int v = (i < n) ? deg[i] : 0;
        buf[threadIdx.x] = v;
        __syncthreads();
        for (int off = 1; off < 1024; off <<= 1) {
            int t = (threadIdx.x >= (unsigned)off) ? buf[threadIdx.x - off] : 0;
            __syncthreads();
            buf[threadIdx.x] += t;
            __syncthreads();
        }
        if (i < n) rowstart[i] = carry + buf[threadIdx.x] - v;
        int blocksum = buf[1023];
        __syncthreads();
        if (threadIdx.x == 0) carry += blocksum;
        __syncthreads();
    }
    if (threadIdx.x == 0) rowstart[n] = carry;
}

__global__ void scatter_kernel(const int* __restrict__ esrc, const int* __restrict__ edst,
                               const int* __restrict__ rowstart, int* __restrict__ cursor,
                               int* __restrict__ s_src, int E, int Etot) {
    int e = blockIdx.x * blockDim.x + threadIdx.x;
    if (e >= Etot) return;
    int src = (e < E) ? esrc[e] : (e - E);
    int dst = (e < E) ? edst[e] : (e - E);
    int pos = rowstart[dst] + atomicAdd(&cursor[dst], 1);
    s_src[pos] = src;
}

// ---- fully fused GATv2 edge phase: 2-edge-pair online softmax, 4-deep gather pipeline ----
__global__ __launch_bounds__(256) void gat_fused_kernel(
        const float* __restrict__ xl, const float* __restrict__ xr,
        const float* __restrict__ att,
        const int* __restrict__ rowstart, const int* __restrict__ s_src,
        float* __restrict__ out) {
    int node = blockIdx.x;
    int h    = threadIdx.x >> 6;
    int lane = threadIdx.x & 63;
    int beg = rowstart[node];
    int end = rowstart[node + 1];
    int c0 = h * CCH + (lane << 1);
    float2 r2 = *(const float2*)(xr + (size_t)node * HCD + c0);
    float2 a2 = *(const float2*)(att + c0);
    float m = -3.0e38f, den = 0.f, acc0 = 0.f, acc1 = 0.f;

    int j = beg;
    float2 q0, q1, q2, q3;
    q0 = *(const float2*)(xl + (size_t)s_src[j] * HCD + c0);   // deg >= 1 (self-loop)
    if (j + 1 < end) q1 = *(const float2*)(xl + (size_t)s_src[j + 1] * HCD + c0);
    if (j + 2 < end) q2 = *(const float2*)(xl + (size_t)s_src[j + 2] * HCD + c0);
    if (j + 3 < end) q3 = *(const float2*)(xl + (size_t)s_src[j + 3] * HCD + c0);

    while (j + 1 < end) {
        float2 A = q0, B = q1;
        q0 = q2; q1 = q3;
        if (j + 4 < end) q2 = *(const float2*)(xl + (size_t)s_src[j + 4] * HCD + c0);
        if (j + 5 < end) q3 = *(const float2*)(xl + (size_t)s_src[j + 5] * HCD + c0);
        float ta0 = A.x + r2.x; ta0 = (ta0 > 0.f) ? ta0 : SLOPE * ta0;
        float ta1 = A.y + r2.y; ta1 = (ta1 > 0.f) ? ta1 : SLOPE * ta1;
        float tb0 = B.x + r2.x; tb0 = (tb0 > 0.f) ? tb0 : SLOPE * tb0;
        float tb1 = B.y + r2.y; tb1 = (tb1 > 0.f) ? tb1 : SLOPE * tb1;
        float sA = fmaf(ta0, a2.x, ta1 * a2.y);
        float sB = fmaf(tb0, a2.x, tb1 * a2.y);
#pragma unroll
        for (int k = 1; k < 64; k <<= 1) {
            sA += __shfl_xor(sA, k);
            sB += __shfl_xor(sB, k);
        }
        float mn = fmaxf(m, fmaxf(sA, sB));
        float sc = expf(m - mn);
        float pA = expf(sA - mn);
        float pB = expf(sB - mn);
        den  = fmaf(den,  sc, pA + pB);
        acc0 = fmaf(acc0, sc, fmaf(pA, A.x, pB * B.x));
        acc1 = fmaf(acc1, sc, fmaf(pA, A.y, pB * B.y));
        m = mn;
        j += 2;
    }
    if (j < end) {   // odd tail
        float2 A = q0;
        float ta0 = A.x + r2.x; ta0 = (ta0 > 0.f) ? ta0 : SLOPE * ta0;
        float ta1 = A.y + r2.y; ta1 = (ta1 > 0.f) ? ta1 : SLOPE * ta1;
        float sA = fmaf(ta0, a2.x, ta1 * a2.y);
#pragma unroll
        for (int k = 1; k < 64; k <<= 1) sA += __shfl_xor(sA, k);
        float mn = fmaxf(m, sA);
        float sc = expf(m - mn);
        float pA = expf(sA - mn);
        den  = fmaf(den,  sc, pA);
        acc0 = fmaf(acc0, sc, pA * A.x);
        acc1 = fmaf(acc1, sc, pA * A.y);
    }
    float inv = 1.0f / (den + 1e-16f);
    *(float2*)(out + (size_t)node * HCD + c0) = make_float2(acc0 * inv, acc1 * inv);
}

// ---- BatchNorm statistics: per-channel sum and sum-of-squares ----
__global__ void bn_stats_kernel(const float* __restrict__ h, float* __restrict__ sum,
                                float* __restrict__ sumsq, int n) {
    int c = blockIdx.y * blockDim.x + threadIdx.x;   // 0..511
    int r0 = blockIdx.x * 128;
    int r1 = min(r0 + 128, n);
    float s = 0.f, s2 = 0.f;
    for (int r = r0; r < r1; ++r) {
        float v = h[(size_t)r * HCD + c];
        s += v;
        s2 = fmaf(v, v, s2);
    }
    atomicAdd(&sum[c], s);
    atomicAdd(&sumsq[c], s2);
}

__global__ void bn_finalize_kernel(const float* __restrict__ sum, const float* __restrict__ sumsq,
                                   const float* __restrict__ g, const float* __restrict__ b,
                                   float* __restrict__ scale, float* __restrict__ shift, int n) {
    int c = threadIdx.x;   // 512
    float inv_n = 1.0f / (float)n;
    float mu = sum[c] * inv_n;
    float var = fmaxf(sumsq[c] * inv_n - mu * mu, 0.0f);
    float sc = g[c] * rsqrtf(var + EPS_BN);
    scale[c] = sc;
    shift[c] = b[c] - mu * sc;
}

// ---- per-graph mean pool with fused BN+ReLU (batch is sorted) ----
__device__ __forceinline__ int lower_bound_i(const int* __restrict__ a, int n, int key) {
    int lo = 0, hi = n;
    while (lo < hi) {
        int mid = (lo + hi) >> 1;
        if (a[mid] < key) lo = mid + 1; else hi = mid;
    }
    return lo;
}

__global__ void pool_bnrelu_kernel(const float* __restrict__ h, const int* __restrict__ batch,
                                   const float* __restrict__ scale, const float* __restrict__ shift,
                                   float* __restrict__ pooled, int n) {
    int g = blockIdx.x;
    int c = threadIdx.x;   // 512
    int start = lower_bound_i(batch, n, g);
    int end   = lower_bound_i(batch, n, g + 1);
    float sc = scale[c], sh = shift[c];
    float s = 0.f;
    for (int r = start; r < end; ++r)
        s += fmaxf(fmaf(h[(size_t)r * HCD + c], sc, sh), 0.f);
    float cnt = (float)max(end - start, 1);
    pooled[(size_t)g * HCD + c] = s / cnt;
}

// ---- MLP head: relu([pooled|gfeat] @ fc1 + b1) @ fc2 + b2 ----
__global__ void head_kernel(const float* __restrict__ pooled, const float* __restrict__ gfeat,
                            const float* __restrict__ fc1w, const float* __restrict__ fc1b,
                            const float* __restrict__ fc2w, const float* __restrict__ fc2b,
                            float* __restrict__ out, int gdim) {
    int g = blockIdx.x;
    int j = threadIdx.x;   // 128
    float acc = fc1b[j];
    const float* prow = pooled + (size_t)g * HCD;
    for (int i = 0; i < HCD; ++i) acc = fmaf(prow[i], fc1w[i * CCH + j], acc);
    const float* grow = gfeat + (size_t)g * gdim;
    for (int i = 0; i < gdim; ++i) acc = fmaf(grow[i], fc1w[(HCD + i) * CCH + j], acc);
    acc = fmaxf(acc, 0.f);
    __shared__ float z[CCH];
    z[j] = acc * fc2w[j];
    __syncthreads();
    for (int s = CCH / 2; s > 0; s >>= 1) {
        if (j < s) z[j] += z[j + s];
        __syncthreads();
    }
    if (j == 0) out[g] = z[0] + fc2b[0];
}

extern "C" void kernel_launch(void* const* d_in, const int* in_sizes, int n_in,
                              void* d_out, int out_size, void* d_ws, size_t ws_size,
                              hipStream_t stream) {
    const float* x     = (const float*)d_in[0];
    const float* gfeat = (const float*)d_in[1];
    const float* W1l   = (const float*)d_in[2];
    const float* b1l   = (const float*)d_in[3];
    const float* W1r   = (const float*)d_in[4];
    const float* b1r   = (const float*)d_in[5];
    const float* att1  = (const float*)d_in[6];
    // d_in[7] = bias1: cancels through BN
    const float* W2l   = (const float*)d_in[8];
    const float* b2l   = (const float*)d_in[9];
    const float* W2r   = (const float*)d_in[10];
    const float* b2r   = (const float*)d_in[11];
    const float* att2  = (const float*)d_in[12];
    // d_in[13] = bias2: cancels through BN
    const float* bn1_g = (const float*)d_in[14];
    const float* bn1_b = (const float*)d_in[15];
    const float* bn2_g = (const float*)d_in[16];
    const float* bn2_b = (const float*)d_in[17];
    const float* fc1w  = (const float*)d_in[18];
    const float* fc1b  = (const float*)d_in[19];
    const float* fc2w  = (const float*)d_in[20];
    const float* fc2b  = (const float*)d_in[21];
    const int* eidx    = (const int*)d_in[22];
    const int* batch   = (const int*)d_in[23];

    const int n    = in_sizes[0] / 9;
    const int E    = in_sizes[22] / 2;
    const int Etot = E + n;
    const int b    = out_size;
    const int gdim = in_sizes[1] / b;
    const int* esrc = eidx;
    const int* edst = eidx + E;

    float* ws = (float*)d_ws;
    size_t nHC = (size_t)n * HCD;
    float* xl      = ws;
    float* xr      = xl + nHC;
    float* hbuf    = xr + nHC;
    int* deg       = (int*)(hbuf + nHC);     // n
    int* rowstart  = deg + n;                // n+1
    int* cursor    = rowstart + n + 1;       // n
    int* s_src     = cursor + n;             // Etot
    float* bnsum   = (float*)(s_src + Etot); // 512
    float* bnsumsq = bnsum + HCD;            // 512
    float* bnscale = bnsumsq + HCD;          // 512
    float* bnshift = bnscale + HCD;          // 512
    float* pooled  = bnshift + HCD;          // b*512
    unsigned short* Ah   = (unsigned short*)(pooled + (size_t)b * HCD);  // n*512 bf16
    unsigned short* Al   = Ah + nHC;
    unsigned short* BThl = Al + nHC;         // 512*512 each
    unsigned short* BTll = BThl + HCD * HCD;
    unsigned short* BThr = BTll + HCD * HCD;
    unsigned short* BTlr = BThr + HCD * HCD;

    const int BLK = 256;
    const int linBlocks  = (int)((nHC + BLK - 1) / BLK);
    const int eBlocks    = (Etot + BLK - 1) / BLK;
    const int bnxBlocks  = (n + 127) / 128;
    const int saBlocks   = (int)((nHC / 4 + BLK - 1) / BLK);
    const int nrt        = (n + 127) / 128;
    dim3 gemmGrid(nrt * 8);

    // ---------------- CSR build (shared by both layers) ----------------
    hipMemsetAsync(deg, 0, (size_t)(2 * n + 1) * sizeof(int), stream);
    hipMemsetAsync(cursor, 0, (size_t)n * sizeof(int), stream);
    hist_kernel<<<eBlocks, BLK, 0, stream>>>(edst, deg, E, Etot);
    scan_kernel<<<1, 1024, 0, stream>>>(deg, rowstart, n);
    scatter_kernel<<<eBlocks, BLK, 0, stream>>>(esrc, edst, rowstart, cursor, s_src, E, Etot);
    // weight split/transpose (graph-independent)
    splitBT_kernel<<<(HCD * HCD) / BLK, BLK, 0, stream>>>(W2l, W2r, BThl, BTll, BThr, BTlr);

    // ---------------- layer 1 ----------------
    lin1_kernel<<<linBlocks, BLK, 0, stream>>>(x, W1l, b1l, W1r, b1r, xl, xr, n);
    gat_fused_kernel<<<n, 256, 0, stream>>>(xl, xr, att1, rowstart, s_src, hbuf);
    hipMemsetAsync(bnsum, 0, HCD * 2 * sizeof(float), stream);
    bn_stats_kernel<<<dim3(bnxBlocks, 2), BLK, 0, stream>>>(hbuf, bnsum, bnsumsq, n);
    bn_finalize_kernel<<<1, HCD, 0, stream>>>(bnsum, bnsumsq, bn1_g, bn1_b, bnscale, bnshift, n);

    // ---------------- layer 2: BN1+ReLU fused into split; MFMA GEMM ----------------
    splitA_kernel<<<saBlocks, BLK, 0, stream>>>(hbuf, bnscale, bnshift, Ah, Al, (int)(nHC / 4));
    gemm_mfma_kernel<<<gemmGrid, BLK, 0, stream>>>(Ah, Al, BThl, BTll, BThr, BTlr,
                                                   b2l, b2r, xl, xr, n);
    gat_fused_kernel<<<n, 256, 0, stream>>>(xl, xr, att2, rowstart, s_src, hbuf);
    hipMemsetAsync(bnsum, 0, HCD * 2 * sizeof(float), stream);
    bn_stats_kernel<<<dim3(bnxBlocks, 2), BLK, 0, stream>>>(hbuf, bnsum, bnsumsq, n);
    bn_finalize_kernel<<<1, HCD, 0, stream>>>(bnsum, bnsumsq, bn2_g, bn2_b, bnscale, bnshift, n);

    // ---------------- readout (BN2+ReLU fused into pool) ----------------
    pool_bnrelu_kernel<<<b, HCD, 0, stream>>>(hbuf, batch, bnscale, bnshift, pooled, n);
    head_kernel<<<b, CCH, 0, stream>>>(pooled, gfeat, fc1w, fc1b, fc2w, fc2b, (float*)d_out, gdim);
}